// Round 1
// baseline (272.861 us; speedup 1.0000x reference)
//
#include <hip/hip_runtime.h>
#include <hip/hip_bf16.h>

// Problem constants (SOnEquivalentLayer)
#define N_ATOMS 20000
#define N_EDGES 200000
#define CCH     64      // channels
#define KRBF    20      // radial features
#define RCUT    5.0f
#define INV_NORM 0.1f   // 1/norm_factor
#define PI_F    3.14159265358979323846f
#define MCAP    20000   // message pool capacity (~6x expected ~3.3k active edges)
#define ACAP    6000    // active-atom capacity (~2x expected ~3.0k)
// LDS geometry: plane stride 72 shorts (144B) keeps 16B alignment for the
// b128 MFMA A-reads AND staggers plane p's base to bank 4p -- with the old
// 64-short stride every plane base wrapped to bank 0 and the t1/t2 staging
// scatter was a ~4-8 way conflict (4.04M conflict cycles measured).
#define PST     72
#define XSTRIDE (13 * PST)   // 936 shorts per atom row; 936*2*16 = 29,952 B LDS
#define FLAT    832          // 13*64 values per atom
#define EF_BLOCKS 782        // ceil(N_EDGES/256)

typedef short v8s __attribute__((ext_vector_type(8)));   // 8 bf16 MFMA A/B frag
typedef short v4s __attribute__((ext_vector_type(4)));   // 4 bf16
typedef float v4f __attribute__((ext_vector_type(4)));   // 4 fp32 MFMA C/D frag

__device__ __forceinline__ float sigm(float x) { return 1.0f / (1.0f + __expf(-x)); }

__device__ __forceinline__ short f2bf(float x) {
    union { float f; unsigned u; } v; v.f = x;
    unsigned r = v.u + 0x7FFFu + ((v.u >> 16) & 1u);
    return (short)(r >> 16);
}
__device__ __forceinline__ float bf2f(short b) {
    union { unsigned u; float f; } v; v.u = ((unsigned)(unsigned short)b) << 16;
    return v.f;
}

// ---------------------------------------------------------------------------
// Phase A (fused): edge cutoff filter + one-time W-fragment precompute.
// slotOf protocol is ZERO-based-free (0 = unassigned, stored value = slot+1)
// so the entire workspace is initialized by ONE memset.
// ---------------------------------------------------------------------------
__global__ __launch_bounds__(256) void edge_wfrag_kernel(
    const float* __restrict__ coords,
    const int*   __restrict__ edge_index,
    const float* __restrict__ w0,
    const float* __restrict__ w1,
    const float* __restrict__ w2,
    float4*      __restrict__ mu,
    float*       __restrict__ mb,
    int*         __restrict__ maj,
    int*         __restrict__ mai,
    int*         __restrict__ slotOf,
    int*         __restrict__ counters,
    short*       __restrict__ wfpre)
{
    if (blockIdx.x >= EF_BLOCKS) {
        // --- wfrag part: layout [wid][way][half][lane][8] bf16 ---
        const int id   = (blockIdx.x - EF_BLOCKS) * 256 + threadIdx.x; // 48*256
        const int j    = id & 7;
        const int lane = (id >> 3) & 63;
        const int h    = (id >> 9) & 1;
        const int rest = id >> 10;               // wid*3 + w, in [0,12)
        const int w    = rest % 3;
        const int wid  = rest / 3;
        const float* Ws = (w == 0) ? w0 : (w == 1) ? w1 : w2;
        const int k = h * 32 + (lane >> 4) * 8 + j;      // input channel
        const int o = wid * 16 + (lane & 15);            // output channel
        wfpre[id] = f2bf(Ws[k * CCH + o]);
        return;
    }

    const int e = blockIdx.x * 256 + threadIdx.x;
    if (e >= N_EDGES) return;
    const int ai = edge_index[e];
    const int aj = edge_index[N_EDGES + e];

    const float rx = coords[aj * 3 + 0] - coords[ai * 3 + 0];
    const float ry = coords[aj * 3 + 1] - coords[ai * 3 + 1];
    const float rz = coords[aj * 3 + 2] - coords[ai * 3 + 2];
    const float d  = sqrtf(rx * rx + ry * ry + rz * rz + 1e-12f);
    if (d >= RCUT) return;   // fc == 0 exactly -> zero contribution

    const float inv_d = 1.0f / d;
    const float base  = PI_F * (d * (1.0f / RCUT));
    const float fc    = 0.5f * (cosf(base) + 1.0f);
    const float coef  = 0.632455532033676f * fc * inv_d * INV_NORM;

    const int slot = atomicAdd(&counters[0], 1);
    if (slot >= MCAP) return;
    mu[slot]  = make_float4(rx * inv_d, ry * inv_d, rz * inv_d, coef);
    mb[slot]  = base;
    maj[slot] = aj;
    mai[slot] = ai;
    if (atomicCAS(&slotOf[ai], 0, -2) == 0)
        slotOf[ai] = atomicAdd(&counters[1], 1) + 1;     // stored value = slot+1
}

// ---------------------------------------------------------------------------
// Phase B: wave-per-message scan. PLANE-MAJOR agg (agg[(slot*13+p)*64+c]):
// every wave-atomic hits 64 contiguous floats. Grid bumped 224 -> 832 blocks
// so ~3.3k messages map ~1:1 onto 3328 waves (was ~3.7 serial msgs/wave on
// 224 blocks with 32 CUs idle -- pure latency kernel, parallelism is free).
// ---------------------------------------------------------------------------
__global__ __launch_bounds__(256, 4) void msg_scan_kernel(
    const float* __restrict__ t0,
    const float* __restrict__ t1,
    const float* __restrict__ t2,
    const float* __restrict__ rbf_w,
    const float4* __restrict__ mu,
    const float* __restrict__ mb,
    const int*   __restrict__ maj,
    const int*   __restrict__ mai,
    const int*   __restrict__ slotOf,
    const int*   __restrict__ counters,
    float*       __restrict__ agg)          // [ACAP * 13 * 64], zero-init
{
    const int w    = (int)((blockIdx.x * 256 + threadIdx.x) >> 6);
    const int c    = threadIdx.x & 63;
    const int nw   = gridDim.x * 4;
    const int nMsg = min(counters[0], MCAP);

    for (int s = w; s < nMsg; s += nw) {
        const float4 U   = mu[s];           // wave-uniform broadcast loads
        const float base = mb[s];
        const int   aj   = maj[s];
        const int   ai   = mai[s];
        const int   sIdx = slotOf[ai] - 1;  // zero-based protocol
        if ((unsigned)sIdx >= ACAP) continue;

        float rbf[KRBF];
#pragma unroll
        for (int kk = 0; kk < KRBF; kk++)
            rbf[kk] = U.w * __sinf((float)(kk + 1) * base);

        float fn[11];
#pragma unroll 1
        for (int k = 0; k < 11; k++) {      // unroll 1: cap VGPR pressure
            float acc = 0.0f;
#pragma unroll
            for (int kk = 0; kk < KRBF; kk++)
                acc += rbf[kk] * rbf_w[k * (KRBF * CCH) + kk * CCH + c];
            fn[k] = acc;
        }

        const int cj = aj * CCH + c;
        const float s0 = t0[cj];
        float v[3];
#pragma unroll
        for (int a = 0; a < 3; a++) v[a] = t1[cj * 3 + a];
        float M[9];
#pragma unroll
        for (int e = 0; e < 9; e++) M[e] = t2[cj * 9 + e];

        const float u[3] = { U.x, U.y, U.z };
        const float dvu = v[0] * u[0] + v[1] * u[1] + v[2] * u[2];
        float Mu[3];
#pragma unroll
        for (int a = 0; a < 3; a++)
            Mu[a] = M[a * 3] * u[0] + M[a * 3 + 1] * u[1] + M[a * 3 + 2] * u[2];
        const float uMu = u[0] * Mu[0] + u[1] * Mu[1] + u[2] * Mu[2];

        float* dst = agg + ((size_t)sIdx * 13) * CCH + c;
        atomicAdd(&dst[0], fn[0] * s0 + fn[4] * dvu + fn[9] * uMu);
#pragma unroll
        for (int a = 0; a < 3; a++)
            atomicAdd(&dst[(1 + a) * CCH],
                      fn[1] * s0 * u[a] + fn[3] * v[a] + fn[6] * dvu * u[a] + fn[8] * Mu[a]);
#pragma unroll
        for (int a = 0; a < 3; a++) {
            const float ta = fn[2] * s0 * u[a] + fn[5] * v[a] + fn[10] * Mu[a];
#pragma unroll
            for (int b = 0; b < 3; b++)
                atomicAdd(&dst[(4 + a * 3 + b) * CCH], ta * u[b] + fn[7] * M[a * 3 + b]);
        }
    }
}

// ---------------------------------------------------------------------------
// Phase C: MFMA self-interaction. v2 (latency attack):
//   launch_bounds(256,5): LDS 29,952B x 5 = 146KB/CU -> ALL 1250 blocks
//     co-resident (capacity 1280), zero grid tail, 20 waves/CU.
//   staging: all 13 dwordx4 loads issued before any conversion (reg prefetch,
//     13 loads in flight vs 1 with the old `#pragma unroll 1`).
//   agg add / store: fully unrolled, static indexing, loads batched.
//   PST=72 plane stride kills the staging scatter's bank conflicts.
//   W-frags loaded AFTER staging so its 24 VGPRs don't overlap the 52-VGPR
//     load prefetch window (keeps peak under the 102-reg 5-block cap).
// ---------------------------------------------------------------------------
__global__ __launch_bounds__(256, 5) void si_mfma_kernel(
    const float* __restrict__ t0,
    const float* __restrict__ t1,
    const float* __restrict__ t2,
    const int*   __restrict__ slotOf,
    const float* __restrict__ agg,          // [ACAP * 13 * 64], plane-major
    const short* __restrict__ wfpre,        // [4][3][2][64][8] bf16
    const float* __restrict__ b0,
    const float* __restrict__ actw,
    float* __restrict__ out0,
    float* __restrict__ out1,
    float* __restrict__ out2)
{
    __shared__ __align__(16) short Xl[16 * XSTRIDE];   // 29,952 B
    const int tid  = threadIdx.x;
    const int lane = tid & 63;
    const int wid  = tid >> 6;
    const int n0   = blockIdx.x * 16;

    // --- staging: prefetch all 13 float4 (independent, in flight together) ---
    float4 vb[13];
#pragma unroll
    for (int i = 0; i < 13; i++) {
        const int f4   = tid + i * 256;          // [0, 3328)
        const int atom = f4 / 208;               // 208 float4 per atom
        const int f    = (f4 - atom * 208) * 4;  // element offset in [0,832)
        const int n    = n0 + atom;
        const float* src;
        if (f < 64)       src = t0 + (size_t)n * 64 + f;
        else if (f < 256) src = t1 + (size_t)n * 192 + (f - 64);
        else              src = t2 + (size_t)n * 576 + (f - 256);
        vb[i] = *(const float4*)src;
    }
    // --- convert -> bf16 LDS transpose (PST=72: planes bank-staggered) ---
#pragma unroll
    for (int i = 0; i < 13; i++) {
        const int f4   = tid + i * 256;
        const int atom = f4 / 208;
        const int f    = (f4 - atom * 208) * 4;
        short* xr = &Xl[atom * XSTRIDE];
        const float4 v = vb[i];
        if (f < 64) {
            v4s p; p[0] = f2bf(v.x); p[1] = f2bf(v.y); p[2] = f2bf(v.z); p[3] = f2bf(v.w);
            *(v4s*)&xr[f] = p;                   // plane 0 contiguous
        } else if (f < 256) {
            const int r0 = f - 64;
            const float vv[4] = { v.x, v.y, v.z, v.w };
#pragma unroll
            for (int j = 0; j < 4; j++) {
                const int rem = r0 + j;
                xr[(1 + rem % 3) * PST + rem / 3] = f2bf(vv[j]);
            }
        } else {
            const int r0 = f - 256;
            const float vv[4] = { v.x, v.y, v.z, v.w };
#pragma unroll
            for (int j = 0; j < 4; j++) {
                const int rem = r0 + j;
                xr[(4 + rem % 9) * PST + rem / 9] = f2bf(vv[j]);
            }
        }
    }
    __syncthreads();

    // --- agg add: slotOf as 4x int4, atom loop fully unrolled (static idx) ---
    {
        const int c = lane;
        int slots[16];
#pragma unroll
        for (int q = 0; q < 4; q++) {
            const int4 s4 = *(const int4*)&slotOf[n0 + q * 4];
            slots[q * 4 + 0] = s4.x; slots[q * 4 + 1] = s4.y;
            slots[q * 4 + 2] = s4.z; slots[q * 4 + 3] = s4.w;
        }
#pragma unroll
        for (int atom = 0; atom < 16; atom++) {
            const int slot = slots[atom] - 1;        // zero-based protocol
            if ((unsigned)slot >= ACAP) continue;    // block-uniform skip (~85%)
            short* xr = &Xl[atom * XSTRIDE];
            const float* ap = agg + ((size_t)slot * 13) * CCH + c;
            // wave wid owns planes wid, wid+4, wid+8 (+12 for wid==0):
            // issue the global loads first, then the LDS RMWs.
            const float g0 = ap[wid * CCH];
            const float g1 = ap[(wid + 4) * CCH];
            const float g2 = ap[(wid + 8) * CCH];
            const int o0 = wid * PST + c;
            const int o1 = (wid + 4) * PST + c;
            const int o2 = (wid + 8) * PST + c;
            if (wid == 0) {                           // wave-uniform branch
                const float g3 = ap[12 * CCH];
                const int o3 = 12 * PST + c;
                xr[o3] = f2bf(bf2f(xr[o3]) + g3);
            }
            xr[o0] = f2bf(bf2f(xr[o0]) + g0);
            xr[o1] = f2bf(bf2f(xr[o1]) + g1);
            xr[o2] = f2bf(bf2f(xr[o2]) + g2);
        }
    }
    __syncthreads();

    const int ocol = wid * 16 + (lane & 15);
    // --- W fragments: 6 coalesced b128 loads (loaded late: VGPR peak ctrl) ---
    v8s wf[3][2];
#pragma unroll
    for (int w = 0; w < 3; w++)
#pragma unroll
        for (int h = 0; h < 2; h++)
            wf[w][h] = *(const v8s*)&wfpre[(((wid * 3 + w) * 2 + h) * 64 + lane) * 8];

    // --- 26 MFMAs: 13 planes x 2 k-halves ---
    v4f acc[13] = {};
    const int abase = (lane & 15) * XSTRIDE + (lane >> 4) * 8;
#pragma unroll
    for (int p = 0; p < 13; p++) {
        const int w = (p == 0) ? 0 : (p < 4 ? 1 : 2);
#pragma unroll
        for (int h = 0; h < 2; h++) {
            const v8s a = *(const v8s*)&Xl[abase + p * PST + h * 32];
            acc[p] = __builtin_amdgcn_mfma_f32_16x16x32_bf16(a, wf[w][h], acc[p], 0, 0, 0);
        }
    }
    __syncthreads();   // all MFMA A-reads done before in-place overwrite

    // --- epilogue: gates + residual, RMW in-place (lane-owned positions) ---
    const float aw0  = actw[ocol];
    const float aw1  = actw[CCH + ocol];
    const float aw2  = actw[2 * CCH + ocol];
    const float bias = b0[ocol];
#pragma unroll
    for (int r = 0; r < 4; r++) {
        const int al = (lane >> 4) * 4 + r;      // atom-in-block (C/D row)
        short* xr = &Xl[al * XSTRIDE];

        const float y0 = acc[0][r] + bias;
        const float z0 = y0 * sigm(aw0 * y0);
        xr[ocol] = f2bf(z0 + bf2f(xr[ocol]));

        float nn = 1e-12f;
#pragma unroll
        for (int a = 0; a < 3; a++) nn += acc[1 + a][r] * acc[1 + a][r];
        const float g1 = sigm(aw1 * sqrtf(nn));
#pragma unroll
        for (int a = 0; a < 3; a++) {
            const int off = (1 + a) * PST + ocol;
            xr[off] = f2bf(acc[1 + a][r] * g1 + bf2f(xr[off]));
        }

        float s2 = 1e-12f;
#pragma unroll
        for (int e = 0; e < 9; e++) s2 += acc[4 + e][r] * acc[4 + e][r];
        const float g2 = sigm(aw2 * sqrtf(s2));
#pragma unroll
        for (int e = 0; e < 9; e++) {
            const int off = (4 + e) * PST + ocol;
            xr[off] = f2bf(acc[4 + e][r] * g2 + bf2f(xr[off]));
        }
    }
    __syncthreads();

    // --- store: fully unrolled, mirrors staging mapping (LDS reads batched) ---
#pragma unroll
    for (int i = 0; i < 13; i++) {
        const int f4   = tid + i * 256;
        const int atom = f4 / 208;
        const int f    = (f4 - atom * 208) * 4;
        const int n    = n0 + atom;
        const short* xr = &Xl[atom * XSTRIDE];
        float4 v;
        float* dst;
        if (f < 64) {
            const v4s p = *(const v4s*)&xr[f];
            v.x = bf2f(p[0]); v.y = bf2f(p[1]); v.z = bf2f(p[2]); v.w = bf2f(p[3]);
            dst = out0 + (size_t)n * 64 + f;
        } else if (f < 256) {
            const int r0 = f - 64;
            float vv[4];
#pragma unroll
            for (int j = 0; j < 4; j++) {
                const int rem = r0 + j;
                vv[j] = bf2f(xr[(1 + rem % 3) * PST + rem / 3]);
            }
            v.x = vv[0]; v.y = vv[1]; v.z = vv[2]; v.w = vv[3];
            dst = out1 + (size_t)n * 192 + r0;
        } else {
            const int r0 = f - 256;
            float vv[4];
#pragma unroll
            for (int j = 0; j < 4; j++) {
                const int rem = r0 + j;
                vv[j] = bf2f(xr[(4 + rem % 9) * PST + rem / 9]);
            }
            v.x = vv[0]; v.y = vv[1]; v.z = vv[2]; v.w = vv[3];
            dst = out2 + (size_t)n * 576 + r0;
        }
        *(float4*)dst = v;
    }
}

extern "C" void kernel_launch(void* const* d_in, const int* in_sizes, int n_in,
                              void* d_out, int out_size, void* d_ws, size_t ws_size,
                              hipStream_t stream) {
    const float* t0     = (const float*)d_in[0];
    const float* t1     = (const float*)d_in[1];
    const float* t2     = (const float*)d_in[2];
    const float* coords = (const float*)d_in[3];
    const int*   eidx   = (const int*)d_in[4];
    const float* rbfw   = (const float*)d_in[5];
    const float* w0     = (const float*)d_in[6];
    const float* b0     = (const float*)d_in[7];
    const float* w1     = (const float*)d_in[8];
    const float* w2     = (const float*)d_in[9];
    const float* actw   = (const float*)d_in[10];

    // Workspace: agg | mu | mb | maj | mai | wfpre | slotOf | counters
    float*  agg    = (float*)d_ws;                       // ACAP*832 floats (20 MB)
    float4* mu     = (float4*)(agg + (size_t)ACAP * FLAT);
    float*  mb     = (float*)(mu + MCAP);
    int*    maj    = (int*)(mb + MCAP);
    int*    mai    = maj + MCAP;
    short*  wfpre  = (short*)(mai + MCAP);               // 12288 bf16 (24.6 KB)
    int*    slotOf = (int*)(wfpre + 12288);
    int*    counters = slotOf + N_ATOMS;
    const size_t wsNeed = (size_t)ACAP * FLAT * 4 + (size_t)MCAP * 28
                        + 12288 * 2 + (size_t)N_ATOMS * 4 + 64;
    if (ws_size < wsNeed) return;

    // ONE memset covers agg(0), slotOf(0 = unassigned) and counters(0);
    // mu/mb/maj/mai/wfpre are write-before-read so zeroing them is free.
    hipMemsetAsync(d_ws, 0, wsNeed, stream);

    float* o0 = (float*)d_out;
    float* o1 = o0 + (size_t)N_ATOMS * CCH;
    float* o2 = o1 + (size_t)N_ATOMS * CCH * 3;

    edge_wfrag_kernel<<<EF_BLOCKS + 48, 256, 0, stream>>>(
        coords, eidx, w0, w1, w2, mu, mb, maj, mai, slotOf, counters, wfpre);

    msg_scan_kernel<<<832, 256, 0, stream>>>(
        t0, t1, t2, rbfw, mu, mb, maj, mai, slotOf, counters, agg);

    si_mfma_kernel<<<N_ATOMS / 16, 256, 0, stream>>>(
        t0, t1, t2, slotOf, agg, wfpre, b0, actw, o0, o1, o2);
}

// Round 2
// 265.207 us; speedup vs baseline: 1.0289x; 1.0289x over previous
//
#include <hip/hip_runtime.h>
#include <hip/hip_bf16.h>

// Problem constants (SOnEquivalentLayer)
#define N_ATOMS 20000
#define N_EDGES 200000
#define CCH     64      // channels
#define KRBF    20      // radial features
#define RCUT    5.0f
#define INV_NORM 0.1f   // 1/norm_factor
#define PI_F    3.14159265358979323846f
#define MCAP    20000   // message pool capacity (~6x expected ~3.3k active edges)
#define ACAP    6000    // active-atom capacity (~2x expected ~3.0k)
// LDS geometry: plane stride 72 shorts (144B) keeps 16B alignment for the
// b128 MFMA A-reads AND staggers plane p's base to bank 4p (bank conflicts
// 4.04M -> 2.28M cycles measured R0->R1).
#define PST     72
#define XSTRIDE (13 * PST)   // 936 shorts per atom row; 936*2*16 = 29,952 B LDS
#define FLAT    832          // 13*64 values per atom
#define EF_BLOCKS 782        // ceil(N_EDGES/256)

typedef short v8s __attribute__((ext_vector_type(8)));   // 8 bf16 MFMA A/B frag
typedef short v4s __attribute__((ext_vector_type(4)));   // 4 bf16
typedef float v4f __attribute__((ext_vector_type(4)));   // 4 fp32 MFMA C/D frag

__device__ __forceinline__ float sigm(float x) { return 1.0f / (1.0f + __expf(-x)); }

__device__ __forceinline__ short f2bf(float x) {
    union { float f; unsigned u; } v; v.f = x;
    unsigned r = v.u + 0x7FFFu + ((v.u >> 16) & 1u);
    return (short)(r >> 16);
}
__device__ __forceinline__ float bf2f(short b) {
    union { unsigned u; float f; } v; v.u = ((unsigned)(unsigned short)b) << 16;
    return v.f;
}

// ---------------------------------------------------------------------------
// Phase A (fused): edge cutoff filter + one-time W-fragment precompute.
// slotOf protocol: 0 = unassigned, stored value = slot+1 (zero-memset-free).
// The CAS-winner thread also ZEROES its agg slot (first-touch zeroing) so the
// 20 MB agg memset is gone entirely -- msg_scan is stream-ordered after us.
// ---------------------------------------------------------------------------
__global__ __launch_bounds__(256) void edge_wfrag_kernel(
    const float* __restrict__ coords,
    const int*   __restrict__ edge_index,
    const float* __restrict__ w0,
    const float* __restrict__ w1,
    const float* __restrict__ w2,
    float4*      __restrict__ mu,
    float*       __restrict__ mb,
    int*         __restrict__ maj,
    int*         __restrict__ mai,
    int*         __restrict__ slotOf,
    int*         __restrict__ counters,
    short*       __restrict__ wfpre,
    float*       __restrict__ agg)
{
    if (blockIdx.x >= EF_BLOCKS) {
        // --- wfrag part: layout [wid][way][half][lane][8] bf16 ---
        const int id   = (blockIdx.x - EF_BLOCKS) * 256 + threadIdx.x; // 48*256
        const int j    = id & 7;
        const int lane = (id >> 3) & 63;
        const int h    = (id >> 9) & 1;
        const int rest = id >> 10;               // wid*3 + w, in [0,12)
        const int w    = rest % 3;
        const int wid  = rest / 3;
        const float* Ws = (w == 0) ? w0 : (w == 1) ? w1 : w2;
        const int k = h * 32 + (lane >> 4) * 8 + j;      // input channel
        const int o = wid * 16 + (lane & 15);            // output channel
        wfpre[id] = f2bf(Ws[k * CCH + o]);
        return;
    }

    const int e = blockIdx.x * 256 + threadIdx.x;
    if (e >= N_EDGES) return;
    const int ai = edge_index[e];
    const int aj = edge_index[N_EDGES + e];

    const float rx = coords[aj * 3 + 0] - coords[ai * 3 + 0];
    const float ry = coords[aj * 3 + 1] - coords[ai * 3 + 1];
    const float rz = coords[aj * 3 + 2] - coords[ai * 3 + 2];
    const float d  = sqrtf(rx * rx + ry * ry + rz * rz + 1e-12f);
    if (d >= RCUT) return;   // fc == 0 exactly -> zero contribution

    const float inv_d = 1.0f / d;
    const float base  = PI_F * (d * (1.0f / RCUT));
    const float fc    = 0.5f * (cosf(base) + 1.0f);
    const float coef  = 0.632455532033676f * fc * inv_d * INV_NORM;

    const int slot = atomicAdd(&counters[0], 1);
    if (slot >= MCAP) return;
    mu[slot]  = make_float4(rx * inv_d, ry * inv_d, rz * inv_d, coef);
    mb[slot]  = base;
    maj[slot] = aj;
    mai[slot] = ai;
    if (atomicCAS(&slotOf[ai], 0, -2) == 0) {
        const int sl = atomicAdd(&counters[1], 1);
        slotOf[ai] = sl + 1;                     // stored value = slot+1
        if (sl < ACAP) {                         // first-touch zero of the slot
            float4* az = (float4*)(agg + (size_t)sl * FLAT);
#pragma unroll 4
            for (int q = 0; q < FLAT / 4; q++) az[q] = make_float4(0.f, 0.f, 0.f, 0.f);
        }
    }
}

// ---------------------------------------------------------------------------
// Phase B: wave-per-message scan. PLANE-MAJOR agg (agg[(slot*13+p)*64+c]):
// every wave-atomic hits 64 contiguous floats. 832 blocks ~= 1 msg/wave.
// ---------------------------------------------------------------------------
__global__ __launch_bounds__(256, 4) void msg_scan_kernel(
    const float* __restrict__ t0,
    const float* __restrict__ t1,
    const float* __restrict__ t2,
    const float* __restrict__ rbf_w,
    const float4* __restrict__ mu,
    const float* __restrict__ mb,
    const int*   __restrict__ maj,
    const int*   __restrict__ mai,
    const int*   __restrict__ slotOf,
    const int*   __restrict__ counters,
    float*       __restrict__ agg)          // [ACAP * 13 * 64], slot-zeroed
{
    const int w    = (int)((blockIdx.x * 256 + threadIdx.x) >> 6);
    const int c    = threadIdx.x & 63;
    const int nw   = gridDim.x * 4;
    const int nMsg = min(counters[0], MCAP);

    for (int s = w; s < nMsg; s += nw) {
        const float4 U   = mu[s];           // wave-uniform broadcast loads
        const float base = mb[s];
        const int   aj   = maj[s];
        const int   ai   = mai[s];
        const int   sIdx = slotOf[ai] - 1;  // zero-based protocol
        if ((unsigned)sIdx >= ACAP) continue;

        float rbf[KRBF];
#pragma unroll
        for (int kk = 0; kk < KRBF; kk++)
            rbf[kk] = U.w * __sinf((float)(kk + 1) * base);

        float fn[11];
#pragma unroll 1
        for (int k = 0; k < 11; k++) {      // unroll 1: cap VGPR pressure
            float acc = 0.0f;
#pragma unroll
            for (int kk = 0; kk < KRBF; kk++)
                acc += rbf[kk] * rbf_w[k * (KRBF * CCH) + kk * CCH + c];
            fn[k] = acc;
        }

        const int cj = aj * CCH + c;
        const float s0 = t0[cj];
        float v[3];
#pragma unroll
        for (int a = 0; a < 3; a++) v[a] = t1[cj * 3 + a];
        float M[9];
#pragma unroll
        for (int e = 0; e < 9; e++) M[e] = t2[cj * 9 + e];

        const float u[3] = { U.x, U.y, U.z };
        const float dvu = v[0] * u[0] + v[1] * u[1] + v[2] * u[2];
        float Mu[3];
#pragma unroll
        for (int a = 0; a < 3; a++)
            Mu[a] = M[a * 3] * u[0] + M[a * 3 + 1] * u[1] + M[a * 3 + 2] * u[2];
        const float uMu = u[0] * Mu[0] + u[1] * Mu[1] + u[2] * Mu[2];

        float* dst = agg + ((size_t)sIdx * 13) * CCH + c;
        atomicAdd(&dst[0], fn[0] * s0 + fn[4] * dvu + fn[9] * uMu);
#pragma unroll
        for (int a = 0; a < 3; a++)
            atomicAdd(&dst[(1 + a) * CCH],
                      fn[1] * s0 * u[a] + fn[3] * v[a] + fn[6] * dvu * u[a] + fn[8] * Mu[a]);
#pragma unroll
        for (int a = 0; a < 3; a++) {
            const float ta = fn[2] * s0 * u[a] + fn[5] * v[a] + fn[10] * Mu[a];
#pragma unroll
            for (int b = 0; b < 3; b++)
                atomicAdd(&dst[(4 + a * 3 + b) * CCH], ta * u[b] + fn[7] * M[a * 3 + b]);
        }
    }
}

// ---------------------------------------------------------------------------
// Phase C: MFMA self-interaction. v3:
//   launch_bounds(256,4): VGPR cap 128 -- the R1 cap of 102 (min-waves=5)
//     spilled the 13x float4 prefetch to scratch (+100 MB HBM writes,
//     VGPR_Count collapsed to 48). 4 blocks/CU x 29,952 B = 120 KB LDS,
//     16 waves/CU, staging peak ~95 regs fits with margin.
//   staging: all 13 dwordx4 loads issued before any conversion.
//   PST=72 plane stride: staging scatter bank conflicts 4.04M -> 2.28M.
// ---------------------------------------------------------------------------
__global__ __launch_bounds__(256, 4) void si_mfma_kernel(
    const float* __restrict__ t0,
    const float* __restrict__ t1,
    const float* __restrict__ t2,
    const int*   __restrict__ slotOf,
    const float* __restrict__ agg,          // [ACAP * 13 * 64], plane-major
    const short* __restrict__ wfpre,        // [4][3][2][64][8] bf16
    const float* __restrict__ b0,
    const float* __restrict__ actw,
    float* __restrict__ out0,
    float* __restrict__ out1,
    float* __restrict__ out2)
{
    __shared__ __align__(16) short Xl[16 * XSTRIDE];   // 29,952 B
    const int tid  = threadIdx.x;
    const int lane = tid & 63;
    const int wid  = tid >> 6;
    const int n0   = blockIdx.x * 16;

    // --- staging: prefetch all 13 float4 (independent, in flight together) ---
    float4 vb[13];
#pragma unroll
    for (int i = 0; i < 13; i++) {
        const int f4   = tid + i * 256;          // [0, 3328)
        const int atom = f4 / 208;               // 208 float4 per atom
        const int f    = (f4 - atom * 208) * 4;  // element offset in [0,832)
        const int n    = n0 + atom;
        const float* src;
        if (f < 64)       src = t0 + (size_t)n * 64 + f;
        else if (f < 256) src = t1 + (size_t)n * 192 + (f - 64);
        else              src = t2 + (size_t)n * 576 + (f - 256);
        vb[i] = *(const float4*)src;
    }
    // --- convert -> bf16 LDS transpose (PST=72: planes bank-staggered) ---
#pragma unroll
    for (int i = 0; i < 13; i++) {
        const int f4   = tid + i * 256;
        const int atom = f4 / 208;
        const int f    = (f4 - atom * 208) * 4;
        short* xr = &Xl[atom * XSTRIDE];
        const float4 v = vb[i];
        if (f < 64) {
            v4s p; p[0] = f2bf(v.x); p[1] = f2bf(v.y); p[2] = f2bf(v.z); p[3] = f2bf(v.w);
            *(v4s*)&xr[f] = p;                   // plane 0 contiguous
        } else if (f < 256) {
            const int r0 = f - 64;
            const float vv[4] = { v.x, v.y, v.z, v.w };
#pragma unroll
            for (int j = 0; j < 4; j++) {
                const int rem = r0 + j;
                xr[(1 + rem % 3) * PST + rem / 3] = f2bf(vv[j]);
            }
        } else {
            const int r0 = f - 256;
            const float vv[4] = { v.x, v.y, v.z, v.w };
#pragma unroll
            for (int j = 0; j < 4; j++) {
                const int rem = r0 + j;
                xr[(4 + rem % 9) * PST + rem / 9] = f2bf(vv[j]);
            }
        }
    }
    __syncthreads();

    // --- agg add: slotOf as 4x int4, atom loop fully unrolled (static idx) ---
    {
        const int c = lane;
        int slots[16];
#pragma unroll
        for (int q = 0; q < 4; q++) {
            const int4 s4 = *(const int4*)&slotOf[n0 + q * 4];
            slots[q * 4 + 0] = s4.x; slots[q * 4 + 1] = s4.y;
            slots[q * 4 + 2] = s4.z; slots[q * 4 + 3] = s4.w;
        }
#pragma unroll
        for (int atom = 0; atom < 16; atom++) {
            const int slot = slots[atom] - 1;        // zero-based protocol
            if ((unsigned)slot >= ACAP) continue;    // block-uniform skip (~85%)
            short* xr = &Xl[atom * XSTRIDE];
            const float* ap = agg + ((size_t)slot * 13) * CCH + c;
            // wave wid owns planes wid, wid+4, wid+8 (+12 for wid==0):
            // issue the global loads first, then the LDS RMWs.
            const float g0 = ap[wid * CCH];
            const float g1 = ap[(wid + 4) * CCH];
            const float g2 = ap[(wid + 8) * CCH];
            const int o0 = wid * PST + c;
            const int o1 = (wid + 4) * PST + c;
            const int o2 = (wid + 8) * PST + c;
            if (wid == 0) {                           // wave-uniform branch
                const float g3 = ap[12 * CCH];
                const int o3 = 12 * PST + c;
                xr[o3] = f2bf(bf2f(xr[o3]) + g3);
            }
            xr[o0] = f2bf(bf2f(xr[o0]) + g0);
            xr[o1] = f2bf(bf2f(xr[o1]) + g1);
            xr[o2] = f2bf(bf2f(xr[o2]) + g2);
        }
    }
    __syncthreads();

    const int ocol = wid * 16 + (lane & 15);
    // --- W fragments: 6 coalesced b128 loads (loaded late: VGPR peak ctrl) ---
    v8s wf[3][2];
#pragma unroll
    for (int w = 0; w < 3; w++)
#pragma unroll
        for (int h = 0; h < 2; h++)
            wf[w][h] = *(const v8s*)&wfpre[(((wid * 3 + w) * 2 + h) * 64 + lane) * 8];

    // --- 26 MFMAs: 13 planes x 2 k-halves ---
    v4f acc[13] = {};
    const int abase = (lane & 15) * XSTRIDE + (lane >> 4) * 8;
#pragma unroll
    for (int p = 0; p < 13; p++) {
        const int w = (p == 0) ? 0 : (p < 4 ? 1 : 2);
#pragma unroll
        for (int h = 0; h < 2; h++) {
            const v8s a = *(const v8s*)&Xl[abase + p * PST + h * 32];
            acc[p] = __builtin_amdgcn_mfma_f32_16x16x32_bf16(a, wf[w][h], acc[p], 0, 0, 0);
        }
    }
    __syncthreads();   // all MFMA A-reads done before in-place overwrite

    // --- epilogue: gates + residual, RMW in-place (lane-owned positions) ---
    const float aw0  = actw[ocol];
    const float aw1  = actw[CCH + ocol];
    const float aw2  = actw[2 * CCH + ocol];
    const float bias = b0[ocol];
#pragma unroll
    for (int r = 0; r < 4; r++) {
        const int al = (lane >> 4) * 4 + r;      // atom-in-block (C/D row)
        short* xr = &Xl[al * XSTRIDE];

        const float y0 = acc[0][r] + bias;
        const float z0 = y0 * sigm(aw0 * y0);
        xr[ocol] = f2bf(z0 + bf2f(xr[ocol]));

        float nn = 1e-12f;
#pragma unroll
        for (int a = 0; a < 3; a++) nn += acc[1 + a][r] * acc[1 + a][r];
        const float g1 = sigm(aw1 * sqrtf(nn));
#pragma unroll
        for (int a = 0; a < 3; a++) {
            const int off = (1 + a) * PST + ocol;
            xr[off] = f2bf(acc[1 + a][r] * g1 + bf2f(xr[off]));
        }

        float s2 = 1e-12f;
#pragma unroll
        for (int e = 0; e < 9; e++) s2 += acc[4 + e][r] * acc[4 + e][r];
        const float g2 = sigm(aw2 * sqrtf(s2));
#pragma unroll
        for (int e = 0; e < 9; e++) {
            const int off = (4 + e) * PST + ocol;
            xr[off] = f2bf(acc[4 + e][r] * g2 + bf2f(xr[off]));
        }
    }
    __syncthreads();

    // --- store: fully unrolled, mirrors staging mapping (LDS reads batched) ---
#pragma unroll
    for (int i = 0; i < 13; i++) {
        const int f4   = tid + i * 256;
        const int atom = f4 / 208;
        const int f    = (f4 - atom * 208) * 4;
        const int n    = n0 + atom;
        const short* xr = &Xl[atom * XSTRIDE];
        float4 v;
        float* dst;
        if (f < 64) {
            const v4s p = *(const v4s*)&xr[f];
            v.x = bf2f(p[0]); v.y = bf2f(p[1]); v.z = bf2f(p[2]); v.w = bf2f(p[3]);
            dst = out0 + (size_t)n * 64 + f;
        } else if (f < 256) {
            const int r0 = f - 64;
            float vv[4];
#pragma unroll
            for (int j = 0; j < 4; j++) {
                const int rem = r0 + j;
                vv[j] = bf2f(xr[(1 + rem % 3) * PST + rem / 3]);
            }
            v.x = vv[0]; v.y = vv[1]; v.z = vv[2]; v.w = vv[3];
            dst = out1 + (size_t)n * 192 + r0;
        } else {
            const int r0 = f - 256;
            float vv[4];
#pragma unroll
            for (int j = 0; j < 4; j++) {
                const int rem = r0 + j;
                vv[j] = bf2f(xr[(4 + rem % 9) * PST + rem / 9]);
            }
            v.x = vv[0]; v.y = vv[1]; v.z = vv[2]; v.w = vv[3];
            dst = out2 + (size_t)n * 576 + r0;
        }
        *(float4*)dst = v;
    }
}

extern "C" void kernel_launch(void* const* d_in, const int* in_sizes, int n_in,
                              void* d_out, int out_size, void* d_ws, size_t ws_size,
                              hipStream_t stream) {
    const float* t0     = (const float*)d_in[0];
    const float* t1     = (const float*)d_in[1];
    const float* t2     = (const float*)d_in[2];
    const float* coords = (const float*)d_in[3];
    const int*   eidx   = (const int*)d_in[4];
    const float* rbfw   = (const float*)d_in[5];
    const float* w0     = (const float*)d_in[6];
    const float* b0     = (const float*)d_in[7];
    const float* w1     = (const float*)d_in[8];
    const float* w2     = (const float*)d_in[9];
    const float* actw   = (const float*)d_in[10];

    // Workspace: agg | mu | mb | maj | mai | wfpre | slotOf | counters
    float*  agg    = (float*)d_ws;                       // ACAP*832 floats (20 MB)
    float4* mu     = (float4*)(agg + (size_t)ACAP * FLAT);
    float*  mb     = (float*)(mu + MCAP);
    int*    maj    = (int*)(mb + MCAP);
    int*    mai    = maj + MCAP;
    short*  wfpre  = (short*)(mai + MCAP);               // 12288 bf16 (24.6 KB)
    int*    slotOf = (int*)(wfpre + 12288);
    int*    counters = slotOf + N_ATOMS;
    const size_t wsNeed = (size_t)ACAP * FLAT * 4 + (size_t)MCAP * 28
                        + 12288 * 2 + (size_t)N_ATOMS * 4 + 64;
    if (ws_size < wsNeed) return;

    // Only slotOf + counters need zeroing (80 KB): agg slots are first-touch
    // zeroed by their CAS-winner in edge_wfrag; mu/mb/maj/mai/wfpre are
    // write-before-read.
    hipMemsetAsync(slotOf, 0, (size_t)N_ATOMS * sizeof(int) + 64, stream);

    float* o0 = (float*)d_out;
    float* o1 = o0 + (size_t)N_ATOMS * CCH;
    float* o2 = o1 + (size_t)N_ATOMS * CCH * 3;

    edge_wfrag_kernel<<<EF_BLOCKS + 48, 256, 0, stream>>>(
        coords, eidx, w0, w1, w2, mu, mb, maj, mai, slotOf, counters, wfpre, agg);

    msg_scan_kernel<<<832, 256, 0, stream>>>(
        t0, t1, t2, rbfw, mu, mb, maj, mai, slotOf, counters, agg);

    si_mfma_kernel<<<N_ATOMS / 16, 256, 0, stream>>>(
        t0, t1, t2, slotOf, agg, wfpre, b0, actw, o0, o1, o2);
}

// Round 3
// 230.856 us; speedup vs baseline: 1.1820x; 1.1488x over previous
//
#include <hip/hip_runtime.h>
#include <hip/hip_bf16.h>

// Problem constants (SOnEquivalentLayer)
#define N_ATOMS 20000
#define N_EDGES 200000
#define CCH     64      // channels
#define KRBF    20      // radial features
#define RCUT    5.0f
#define INV_NORM 0.1f   // 1/norm_factor
#define PI_F    3.14159265358979323846f
#define MCAP    20000   // message pool capacity (~6x expected ~3.3k active edges)
#define ACAP    6000    // active-atom capacity (~2x expected ~3.0k)
// LDS geometry: plane stride 72 shorts (144B) keeps 16B alignment for the
// b128 MFMA A-reads AND staggers plane p's base to bank 4p (bank conflicts
// 4.04M -> 2.28M cycles measured R0->R1).
#define PST     72
#define XSTRIDE (13 * PST)   // 936 shorts per atom row; 936*2*16 = 29,952 B LDS
#define FLAT    832          // 13*64 values per atom
#define EF_BLOCKS 782        // ceil(N_EDGES/256)

typedef short v8s __attribute__((ext_vector_type(8)));   // 8 bf16 MFMA A/B frag
typedef short v4s __attribute__((ext_vector_type(4)));   // 4 bf16
typedef float v4f __attribute__((ext_vector_type(4)));   // 4 fp32 MFMA C/D frag

__device__ __forceinline__ float sigm(float x) { return 1.0f / (1.0f + __expf(-x)); }

__device__ __forceinline__ short f2bf(float x) {
    union { float f; unsigned u; } v; v.f = x;
    unsigned r = v.u + 0x7FFFu + ((v.u >> 16) & 1u);
    return (short)(r >> 16);
}
__device__ __forceinline__ float bf2f(short b) {
    union { unsigned u; float f; } v; v.u = ((unsigned)(unsigned short)b) << 16;
    return v.f;
}

// ---------------------------------------------------------------------------
// Phase A (fused): edge cutoff filter + one-time W-fragment precompute.
// slotOf protocol: 0 = unassigned, stored value = slot+1 (zero-memset-free).
// The CAS-winner thread also ZEROES its agg slot (first-touch zeroing) so the
// 20 MB agg memset is gone entirely -- msg_scan is stream-ordered after us.
// ---------------------------------------------------------------------------
__global__ __launch_bounds__(256) void edge_wfrag_kernel(
    const float* __restrict__ coords,
    const int*   __restrict__ edge_index,
    const float* __restrict__ w0,
    const float* __restrict__ w1,
    const float* __restrict__ w2,
    float4*      __restrict__ mu,
    float*       __restrict__ mb,
    int*         __restrict__ maj,
    int*         __restrict__ mai,
    int*         __restrict__ slotOf,
    int*         __restrict__ counters,
    short*       __restrict__ wfpre,
    float*       __restrict__ agg)
{
    if (blockIdx.x >= EF_BLOCKS) {
        // --- wfrag part: layout [wid][way][half][lane][8] bf16 ---
        const int id   = (blockIdx.x - EF_BLOCKS) * 256 + threadIdx.x; // 48*256
        const int j    = id & 7;
        const int lane = (id >> 3) & 63;
        const int h    = (id >> 9) & 1;
        const int rest = id >> 10;               // wid*3 + w, in [0,12)
        const int w    = rest % 3;
        const int wid  = rest / 3;
        const float* Ws = (w == 0) ? w0 : (w == 1) ? w1 : w2;
        const int k = h * 32 + (lane >> 4) * 8 + j;      // input channel
        const int o = wid * 16 + (lane & 15);            // output channel
        wfpre[id] = f2bf(Ws[k * CCH + o]);
        return;
    }

    const int e = blockIdx.x * 256 + threadIdx.x;
    if (e >= N_EDGES) return;
    const int ai = edge_index[e];
    const int aj = edge_index[N_EDGES + e];

    const float rx = coords[aj * 3 + 0] - coords[ai * 3 + 0];
    const float ry = coords[aj * 3 + 1] - coords[ai * 3 + 1];
    const float rz = coords[aj * 3 + 2] - coords[ai * 3 + 2];
    const float d  = sqrtf(rx * rx + ry * ry + rz * rz + 1e-12f);
    if (d >= RCUT) return;   // fc == 0 exactly -> zero contribution

    const float inv_d = 1.0f / d;
    const float base  = PI_F * (d * (1.0f / RCUT));
    const float fc    = 0.5f * (cosf(base) + 1.0f);
    const float coef  = 0.632455532033676f * fc * inv_d * INV_NORM;

    const int slot = atomicAdd(&counters[0], 1);
    if (slot >= MCAP) return;
    mu[slot]  = make_float4(rx * inv_d, ry * inv_d, rz * inv_d, coef);
    mb[slot]  = base;
    maj[slot] = aj;
    mai[slot] = ai;
    if (atomicCAS(&slotOf[ai], 0, -2) == 0) {
        const int sl = atomicAdd(&counters[1], 1);
        slotOf[ai] = sl + 1;                     // stored value = slot+1
        if (sl < ACAP) {                         // first-touch zero of the slot
            float4* az = (float4*)(agg + (size_t)sl * FLAT);
#pragma unroll 4
            for (int q = 0; q < FLAT / 4; q++) az[q] = make_float4(0.f, 0.f, 0.f, 0.f);
        }
    }
}

// ---------------------------------------------------------------------------
// Phase B: wave-per-message scan. PLANE-MAJOR agg (agg[(slot*13+p)*64+c]):
// every wave-atomic hits 64 contiguous floats. 832 blocks ~= 1 msg/wave.
// ---------------------------------------------------------------------------
__global__ __launch_bounds__(256, 4) void msg_scan_kernel(
    const float* __restrict__ t0,
    const float* __restrict__ t1,
    const float* __restrict__ t2,
    const float* __restrict__ rbf_w,
    const float4* __restrict__ mu,
    const float* __restrict__ mb,
    const int*   __restrict__ maj,
    const int*   __restrict__ mai,
    const int*   __restrict__ slotOf,
    const int*   __restrict__ counters,
    float*       __restrict__ agg)          // [ACAP * 13 * 64], slot-zeroed
{
    const int w    = (int)((blockIdx.x * 256 + threadIdx.x) >> 6);
    const int c    = threadIdx.x & 63;
    const int nw   = gridDim.x * 4;
    const int nMsg = min(counters[0], MCAP);

    for (int s = w; s < nMsg; s += nw) {
        const float4 U   = mu[s];           // wave-uniform broadcast loads
        const float base = mb[s];
        const int   aj   = maj[s];
        const int   ai   = mai[s];
        const int   sIdx = slotOf[ai] - 1;  // zero-based protocol
        if ((unsigned)sIdx >= ACAP) continue;

        float rbf[KRBF];
#pragma unroll
        for (int kk = 0; kk < KRBF; kk++)
            rbf[kk] = U.w * __sinf((float)(kk + 1) * base);

        float fn[11];
#pragma unroll 1
        for (int k = 0; k < 11; k++) {      // unroll 1: cap VGPR pressure
            float acc = 0.0f;
#pragma unroll
            for (int kk = 0; kk < KRBF; kk++)
                acc += rbf[kk] * rbf_w[k * (KRBF * CCH) + kk * CCH + c];
            fn[k] = acc;
        }

        const int cj = aj * CCH + c;
        const float s0 = t0[cj];
        float v[3];
#pragma unroll
        for (int a = 0; a < 3; a++) v[a] = t1[cj * 3 + a];
        float M[9];
#pragma unroll
        for (int e = 0; e < 9; e++) M[e] = t2[cj * 9 + e];

        const float u[3] = { U.x, U.y, U.z };
        const float dvu = v[0] * u[0] + v[1] * u[1] + v[2] * u[2];
        float Mu[3];
#pragma unroll
        for (int a = 0; a < 3; a++)
            Mu[a] = M[a * 3] * u[0] + M[a * 3 + 1] * u[1] + M[a * 3 + 2] * u[2];
        const float uMu = u[0] * Mu[0] + u[1] * Mu[1] + u[2] * Mu[2];

        float* dst = agg + ((size_t)sIdx * 13) * CCH + c;
        atomicAdd(&dst[0], fn[0] * s0 + fn[4] * dvu + fn[9] * uMu);
#pragma unroll
        for (int a = 0; a < 3; a++)
            atomicAdd(&dst[(1 + a) * CCH],
                      fn[1] * s0 * u[a] + fn[3] * v[a] + fn[6] * dvu * u[a] + fn[8] * Mu[a]);
#pragma unroll
        for (int a = 0; a < 3; a++) {
            const float ta = fn[2] * s0 * u[a] + fn[5] * v[a] + fn[10] * Mu[a];
#pragma unroll
            for (int b = 0; b < 3; b++)
                atomicAdd(&dst[(4 + a * 3 + b) * CCH], ta * u[b] + fn[7] * M[a * 3 + b]);
        }
    }
}

// ---------------------------------------------------------------------------
// Phase C: MFMA self-interaction. v4:
//   Staging/store back to `#pragma unroll 1` (R0-proven: 62us, VGPR 52, no
//   spill). The 13x float4 full prefetch spilled at EVERY cap tried (R1:
//   cap 102 -> 48 regs + 100MB scratch; R2: cap 128 -> compiler still chose
//   64 regs + 39MB scratch). Compiler will not hold 52 VGPRs of payload;
//   depth-1 cur/nxt pipeline gets 2 loads in flight at only 8 payload regs.
//   PST=72 plane stride kept (conflicts 4.04M -> 2.28M).
// ---------------------------------------------------------------------------
__device__ __forceinline__ const float* stage_src(
    const float* __restrict__ t0, const float* __restrict__ t1,
    const float* __restrict__ t2, int n0, int f4, int& atom, int& f)
{
    atom = f4 / 208;                 // 208 float4 per atom
    f = (f4 - atom * 208) * 4;       // element offset in [0,832)
    const int n = n0 + atom;
    if (f < 64)  return t0 + (size_t)n * 64 + f;
    if (f < 256) return t1 + (size_t)n * 192 + (f - 64);
    return t2 + (size_t)n * 576 + (f - 256);
}

__global__ __launch_bounds__(256, 4) void si_mfma_kernel(
    const float* __restrict__ t0,
    const float* __restrict__ t1,
    const float* __restrict__ t2,
    const int*   __restrict__ slotOf,
    const float* __restrict__ agg,          // [ACAP * 13 * 64], plane-major
    const short* __restrict__ wfpre,        // [4][3][2][64][8] bf16
    const float* __restrict__ b0,
    const float* __restrict__ actw,
    float* __restrict__ out0,
    float* __restrict__ out1,
    float* __restrict__ out2)
{
    __shared__ __align__(16) short Xl[16 * XSTRIDE];   // 29,952 B
    const int tid  = threadIdx.x;
    const int lane = tid & 63;
    const int wid  = tid >> 6;
    const int n0   = blockIdx.x * 16;

    // --- staging: depth-1 pipelined loop (2 loads in flight, 8 payload regs) ---
    {
        int atomc, fc;
        const float* p0 = stage_src(t0, t1, t2, n0, tid, atomc, fc);
        float4 cur = *(const float4*)p0;
#pragma unroll 1
        for (int i = 0; i < 13; i++) {
            float4 nxt = make_float4(0.f, 0.f, 0.f, 0.f);
            int atomn = 0, fnx = 0;
            if (i < 12) {
                const float* pn = stage_src(t0, t1, t2, n0, tid + (i + 1) * 256, atomn, fnx);
                nxt = *(const float4*)pn;    // issued before cur is consumed
            }
            short* xr = &Xl[atomc * XSTRIDE];
            if (fc < 64) {
                v4s p; p[0] = f2bf(cur.x); p[1] = f2bf(cur.y);
                p[2] = f2bf(cur.z); p[3] = f2bf(cur.w);
                *(v4s*)&xr[fc] = p;              // plane 0 contiguous
            } else if (fc < 256) {
                const int r0 = fc - 64;
                const float vv[4] = { cur.x, cur.y, cur.z, cur.w };
#pragma unroll
                for (int j = 0; j < 4; j++) {
                    const int rem = r0 + j;
                    xr[(1 + rem % 3) * PST + rem / 3] = f2bf(vv[j]);
                }
            } else {
                const int r0 = fc - 256;
                const float vv[4] = { cur.x, cur.y, cur.z, cur.w };
#pragma unroll
                for (int j = 0; j < 4; j++) {
                    const int rem = r0 + j;
                    xr[(4 + rem % 9) * PST + rem / 9] = f2bf(vv[j]);
                }
            }
            cur = nxt; atomc = atomn; fc = fnx;
        }
    }
    __syncthreads();

    // --- agg add: slotOf as 4x int4, atom loop fully unrolled (static idx) ---
    {
        const int c = lane;
        int slots[16];
#pragma unroll
        for (int q = 0; q < 4; q++) {
            const int4 s4 = *(const int4*)&slotOf[n0 + q * 4];
            slots[q * 4 + 0] = s4.x; slots[q * 4 + 1] = s4.y;
            slots[q * 4 + 2] = s4.z; slots[q * 4 + 3] = s4.w;
        }
#pragma unroll
        for (int atom = 0; atom < 16; atom++) {
            const int slot = slots[atom] - 1;        // zero-based protocol
            if ((unsigned)slot >= ACAP) continue;    // block-uniform skip (~85%)
            short* xr = &Xl[atom * XSTRIDE];
            const float* ap = agg + ((size_t)slot * 13) * CCH + c;
            // wave wid owns planes wid, wid+4, wid+8 (+12 for wid==0):
            // issue the global loads first, then the LDS RMWs.
            const float g0 = ap[wid * CCH];
            const float g1 = ap[(wid + 4) * CCH];
            const float g2 = ap[(wid + 8) * CCH];
            const int o0 = wid * PST + c;
            const int o1 = (wid + 4) * PST + c;
            const int o2 = (wid + 8) * PST + c;
            if (wid == 0) {                           // wave-uniform branch
                const float g3 = ap[12 * CCH];
                const int o3 = 12 * PST + c;
                xr[o3] = f2bf(bf2f(xr[o3]) + g3);
            }
            xr[o0] = f2bf(bf2f(xr[o0]) + g0);
            xr[o1] = f2bf(bf2f(xr[o1]) + g1);
            xr[o2] = f2bf(bf2f(xr[o2]) + g2);
        }
    }
    __syncthreads();

    const int ocol = wid * 16 + (lane & 15);
    // --- W fragments: 6 coalesced b128 loads (loaded late: VGPR peak ctrl) ---
    v8s wf[3][2];
#pragma unroll
    for (int w = 0; w < 3; w++)
#pragma unroll
        for (int h = 0; h < 2; h++)
            wf[w][h] = *(const v8s*)&wfpre[(((wid * 3 + w) * 2 + h) * 64 + lane) * 8];

    // --- 26 MFMAs: 13 planes x 2 k-halves ---
    v4f acc[13] = {};
    const int abase = (lane & 15) * XSTRIDE + (lane >> 4) * 8;
#pragma unroll
    for (int p = 0; p < 13; p++) {
        const int w = (p == 0) ? 0 : (p < 4 ? 1 : 2);
#pragma unroll
        for (int h = 0; h < 2; h++) {
            const v8s a = *(const v8s*)&Xl[abase + p * PST + h * 32];
            acc[p] = __builtin_amdgcn_mfma_f32_16x16x32_bf16(a, wf[w][h], acc[p], 0, 0, 0);
        }
    }
    __syncthreads();   // all MFMA A-reads done before in-place overwrite

    // --- epilogue: gates + residual, RMW in-place (lane-owned positions) ---
    const float aw0  = actw[ocol];
    const float aw1  = actw[CCH + ocol];
    const float aw2  = actw[2 * CCH + ocol];
    const float bias = b0[ocol];
#pragma unroll
    for (int r = 0; r < 4; r++) {
        const int al = (lane >> 4) * 4 + r;      // atom-in-block (C/D row)
        short* xr = &Xl[al * XSTRIDE];

        const float y0 = acc[0][r] + bias;
        const float z0 = y0 * sigm(aw0 * y0);
        xr[ocol] = f2bf(z0 + bf2f(xr[ocol]));

        float nn = 1e-12f;
#pragma unroll
        for (int a = 0; a < 3; a++) nn += acc[1 + a][r] * acc[1 + a][r];
        const float g1 = sigm(aw1 * sqrtf(nn));
#pragma unroll
        for (int a = 0; a < 3; a++) {
            const int off = (1 + a) * PST + ocol;
            xr[off] = f2bf(acc[1 + a][r] * g1 + bf2f(xr[off]));
        }

        float s2 = 1e-12f;
#pragma unroll
        for (int e = 0; e < 9; e++) s2 += acc[4 + e][r] * acc[4 + e][r];
        const float g2 = sigm(aw2 * sqrtf(s2));
#pragma unroll
        for (int e = 0; e < 9; e++) {
            const int off = (4 + e) * PST + ocol;
            xr[off] = f2bf(acc[4 + e][r] * g2 + bf2f(xr[off]));
        }
    }
    __syncthreads();

    // --- store: unroll-1 loop mirroring staging mapping (no bulk hoisting) ---
#pragma unroll 1
    for (int i = 0; i < 13; i++) {
        const int f4   = tid + i * 256;
        const int atom = f4 / 208;
        const int f    = (f4 - atom * 208) * 4;
        const int n    = n0 + atom;
        const short* xr = &Xl[atom * XSTRIDE];
        float4 v;
        float* dst;
        if (f < 64) {
            const v4s p = *(const v4s*)&xr[f];
            v.x = bf2f(p[0]); v.y = bf2f(p[1]); v.z = bf2f(p[2]); v.w = bf2f(p[3]);
            dst = out0 + (size_t)n * 64 + f;
        } else if (f < 256) {
            const int r0 = f - 64;
            float vv[4];
#pragma unroll
            for (int j = 0; j < 4; j++) {
                const int rem = r0 + j;
                vv[j] = bf2f(xr[(1 + rem % 3) * PST + rem / 3]);
            }
            v.x = vv[0]; v.y = vv[1]; v.z = vv[2]; v.w = vv[3];
            dst = out1 + (size_t)n * 192 + r0;
        } else {
            const int r0 = f - 256;
            float vv[4];
#pragma unroll
            for (int j = 0; j < 4; j++) {
                const int rem = r0 + j;
                vv[j] = bf2f(xr[(4 + rem % 9) * PST + rem / 9]);
            }
            v.x = vv[0]; v.y = vv[1]; v.z = vv[2]; v.w = vv[3];
            dst = out2 + (size_t)n * 576 + r0;
        }
        *(float4*)dst = v;
    }
}

extern "C" void kernel_launch(void* const* d_in, const int* in_sizes, int n_in,
                              void* d_out, int out_size, void* d_ws, size_t ws_size,
                              hipStream_t stream) {
    const float* t0     = (const float*)d_in[0];
    const float* t1     = (const float*)d_in[1];
    const float* t2     = (const float*)d_in[2];
    const float* coords = (const float*)d_in[3];
    const int*   eidx   = (const int*)d_in[4];
    const float* rbfw   = (const float*)d_in[5];
    const float* w0     = (const float*)d_in[6];
    const float* b0     = (const float*)d_in[7];
    const float* w1     = (const float*)d_in[8];
    const float* w2     = (const float*)d_in[9];
    const float* actw   = (const float*)d_in[10];

    // Workspace: agg | mu | mb | maj | mai | wfpre | slotOf | counters
    float*  agg    = (float*)d_ws;                       // ACAP*832 floats (20 MB)
    float4* mu     = (float4*)(agg + (size_t)ACAP * FLAT);
    float*  mb     = (float*)(mu + MCAP);
    int*    maj    = (int*)(mb + MCAP);
    int*    mai    = maj + MCAP;
    short*  wfpre  = (short*)(mai + MCAP);               // 12288 bf16 (24.6 KB)
    int*    slotOf = (int*)(wfpre + 12288);
    int*    counters = slotOf + N_ATOMS;
    const size_t wsNeed = (size_t)ACAP * FLAT * 4 + (size_t)MCAP * 28
                        + 12288 * 2 + (size_t)N_ATOMS * 4 + 64;
    if (ws_size < wsNeed) return;

    // Only slotOf + counters need zeroing (80 KB): agg slots are first-touch
    // zeroed by their CAS-winner in edge_wfrag; mu/mb/maj/mai/wfpre are
    // write-before-read.
    hipMemsetAsync(slotOf, 0, (size_t)N_ATOMS * sizeof(int) + 64, stream);

    float* o0 = (float*)d_out;
    float* o1 = o0 + (size_t)N_ATOMS * CCH;
    float* o2 = o1 + (size_t)N_ATOMS * CCH * 3;

    edge_wfrag_kernel<<<EF_BLOCKS + 48, 256, 0, stream>>>(
        coords, eidx, w0, w1, w2, mu, mb, maj, mai, slotOf, counters, wfpre, agg);

    msg_scan_kernel<<<832, 256, 0, stream>>>(
        t0, t1, t2, rbfw, mu, mb, maj, mai, slotOf, counters, agg);

    si_mfma_kernel<<<N_ATOMS / 16, 256, 0, stream>>>(
        t0, t1, t2, slotOf, agg, wfpre, b0, actw, o0, o1, o2);
}

// Round 4
// 173.768 us; speedup vs baseline: 1.5703x; 1.3285x over previous
//
#include <hip/hip_runtime.h>
#include <hip/hip_bf16.h>

// Problem constants (SOnEquivalentLayer)
#define N_ATOMS 20000
#define N_EDGES 200000
#define CCH     64      // channels
#define KRBF    20      // radial features
#define RCUT    5.0f
#define INV_NORM 0.1f   // 1/norm_factor
#define PI_F    3.14159265358979323846f
#define MCAP    20000   // message pool capacity (~6x expected ~3.3k active edges)
#define ACAP    6000    // active-atom capacity (~2x expected ~3.0k)
#define NSHARD  16      // counter shards (separate cache lines)
#define SEGM    (MCAP / NSHARD)   // 1250 msgs per shard (~206 expected)
#define ASEG    (ACAP / NSHARD)   // 375 atom slots per shard (~190 expected)
// LDS geometry: plane stride 72 shorts (144B) keeps 16B alignment for the
// b128 MFMA A-reads AND staggers plane p's base to bank 4p (bank conflicts
// 4.04M -> 2.28M cycles measured R0->R1).
#define PST     72
#define XSTRIDE (13 * PST)   // 936 shorts per atom row; 936*2*16 = 29,952 B LDS
#define FLAT    832          // 13*64 values per atom
#define EF_BLOCKS 782        // ceil(N_EDGES/256)

// counters region: 1024 ints (4 KB). cnt0[i] at [i*32], cnt1[i] at [512+i*32]
#define CNT0(c, i) (c)[(i) * 32]
#define CNT1(c, i) (c)[512 + (i) * 32]

typedef short v8s __attribute__((ext_vector_type(8)));   // 8 bf16 MFMA A/B frag
typedef short v4s __attribute__((ext_vector_type(4)));   // 4 bf16
typedef float v4f __attribute__((ext_vector_type(4)));   // 4 fp32 MFMA C/D frag

__device__ __forceinline__ float sigm(float x) { return 1.0f / (1.0f + __expf(-x)); }

__device__ __forceinline__ short f2bf(float x) {
    union { float f; unsigned u; } v; v.f = x;
    unsigned r = v.u + 0x7FFFu + ((v.u >> 16) & 1u);
    return (short)(r >> 16);
}
__device__ __forceinline__ float bf2f(short b) {
    union { unsigned u; float f; } v; v.u = ((unsigned)(unsigned short)b) << 16;
    return v.f;
}

// ---------------------------------------------------------------------------
// Phase A (fused): edge cutoff filter + one-time W-fragment precompute.
// R3 post-mortem: this kernel was 68us with VALUBusy 1.4%, HBM 2.2% -- a
// pure serialization chain: ~6k atomics (counters[0]+counters[1]) all in ONE
// cache line, serialized cross-XCD. v5 fixes:
//   - 16-way sharded counters on separate 128B-spaced lines (blockIdx&15)
//   - wave-aggregated allocation: ballot -> popcount -> ONE atomicAdd/wave,
//     base broadcast via readfirstlane, per-lane offset via mask prefix
//     (requires alive-predication instead of early returns)
//   - winner agg-slot zeroing done cooperatively by the FULL wave (4x float4
//     per lane, coalesced) instead of 208 serial stores from one lane
// slotOf protocol: 0 = unassigned, stored = slot+1, ACAP+1 = overflow/invalid.
// ---------------------------------------------------------------------------
__global__ __launch_bounds__(256) void edge_wfrag_kernel(
    const float* __restrict__ coords,
    const int*   __restrict__ edge_index,
    const float* __restrict__ w0,
    const float* __restrict__ w1,
    const float* __restrict__ w2,
    float4*      __restrict__ mu,
    float*       __restrict__ mb,
    int*         __restrict__ maj,
    int*         __restrict__ mai,
    int*         __restrict__ slotOf,
    int*         __restrict__ cnts,
    short*       __restrict__ wfpre,
    float*       __restrict__ agg)
{
    if (blockIdx.x >= EF_BLOCKS) {
        // --- wfrag part: layout [wid][way][half][lane][8] bf16 ---
        const int id   = (blockIdx.x - EF_BLOCKS) * 256 + threadIdx.x; // 48*256
        const int j    = id & 7;
        const int lane = (id >> 3) & 63;
        const int h    = (id >> 9) & 1;
        const int rest = id >> 10;               // wid*3 + w, in [0,12)
        const int w    = rest % 3;
        const int wid  = rest / 3;
        const float* Ws = (w == 0) ? w0 : (w == 1) ? w1 : w2;
        const int k = h * 32 + (lane >> 4) * 8 + j;      // input channel
        const int o = wid * 16 + (lane & 15);            // output channel
        wfpre[id] = f2bf(Ws[k * CCH + o]);
        return;
    }

    const int e     = blockIdx.x * 256 + threadIdx.x;
    const int lane  = threadIdx.x & 63;
    const int shard = blockIdx.x & (NSHARD - 1);

    bool alive = (e < N_EDGES);
    int ai = 0, aj = 0;
    float rx = 0.f, ry = 0.f, rz = 0.f, d = 1.0f;
    if (alive) {
        ai = edge_index[e];
        aj = edge_index[N_EDGES + e];
        rx = coords[aj * 3 + 0] - coords[ai * 3 + 0];
        ry = coords[aj * 3 + 1] - coords[ai * 3 + 1];
        rz = coords[aj * 3 + 2] - coords[ai * 3 + 2];
        d  = sqrtf(rx * rx + ry * ry + rz * rz + 1e-12f);
        if (d >= RCUT) alive = false;   // fc == 0 exactly -> zero contribution
    }

    int myZeroSlot = -1;
    if (alive) {                        // exec == surviving lanes
        const float inv_d = 1.0f / d;
        const float base  = PI_F * (d * (1.0f / RCUT));
        const float fcv   = 0.5f * (cosf(base) + 1.0f);
        const float coef  = 0.632455532033676f * fcv * inv_d * INV_NORM;

        // wave-aggregated message-slot allocation (1 atomic per wave)
        const unsigned long long m = __ballot(1);
        const int pfx = __popcll(m & ((1ull << lane) - 1ull));
        int wbase = 0;
        if (pfx == 0) wbase = atomicAdd(&CNT0(cnts, shard), __popcll(m));
        wbase = __builtin_amdgcn_readfirstlane(wbase);
        const int loc = wbase + pfx;
        if (loc < SEGM) {
            const int slot = shard * SEGM + loc;
            mu[slot]  = make_float4(rx * inv_d, ry * inv_d, rz * inv_d, coef);
            mb[slot]  = base;
            maj[slot] = aj;
            mai[slot] = ai;
        }

        if (atomicCAS(&slotOf[ai], 0, -2) == 0) {   // exec == winner lanes
            const unsigned long long wm = __ballot(1);
            const int wpfx = __popcll(wm & ((1ull << lane) - 1ull));
            int wb = 0;
            if (wpfx == 0) wb = atomicAdd(&CNT1(cnts, shard), __popcll(wm));
            wb = __builtin_amdgcn_readfirstlane(wb);
            const int sl = wb + wpfx;
            if (sl < ASEG) {
                const int g = shard * ASEG + sl;
                slotOf[ai] = g + 1;                  // stored value = slot+1
                myZeroSlot = g;
            } else {
                slotOf[ai] = ACAP + 1;               // overflow -> invalid
            }
        }
    }

    // full exec: cooperative zero of each winner's agg slot (coalesced)
    unsigned long long zm = __ballot(myZeroSlot >= 0);
    while (zm) {
        const int src = (int)__builtin_ctzll(zm);
        zm &= zm - 1;
        const int g = __shfl(myZeroSlot, src);
        float4* az = (float4*)(agg + (size_t)g * FLAT);
#pragma unroll
        for (int q = 0; q < 4; q++) {
            const int idx = lane + q * 64;
            if (idx < FLAT / 4) az[idx] = make_float4(0.f, 0.f, 0.f, 0.f);
        }
    }
}

// ---------------------------------------------------------------------------
// Phase B: wave-per-message scan over 16 message segments. PLANE-MAJOR agg
// (agg[(slot*13+p)*64+c]): every wave-atomic hits 64 contiguous floats.
// Segment lookup per message is an unrolled constant-indexed select chain
// (registers only -- runtime-indexed local arrays go to scratch, rule #20).
// ---------------------------------------------------------------------------
__global__ __launch_bounds__(256, 4) void msg_scan_kernel(
    const float* __restrict__ t0,
    const float* __restrict__ t1,
    const float* __restrict__ t2,
    const float* __restrict__ rbf_w,
    const float4* __restrict__ mu,
    const float* __restrict__ mb,
    const int*   __restrict__ maj,
    const int*   __restrict__ mai,
    const int*   __restrict__ slotOf,
    const int*   __restrict__ cnts,
    float*       __restrict__ agg)          // [ACAP * 13 * 64], slot-zeroed
{
    const int w    = (int)((blockIdx.x * 256 + threadIdx.x) >> 6);
    const int c    = threadIdx.x & 63;
    const int nw   = gridDim.x * 4;

    int pr[NSHARD];      // prefix before shard i (const-indexed in unrolls)
    int run = 0;
#pragma unroll
    for (int i = 0; i < NSHARD; i++) {
        pr[i] = run;
        run += min(CNT0(cnts, i), SEGM);
    }
    const int T = run;

    for (int mg = w; mg < T; mg += nw) {
        int s = mg;                          // pooled slot for segment 0
#pragma unroll
        for (int i = 1; i < NSHARD; i++)
            if (mg >= pr[i]) s = i * SEGM + (mg - pr[i]);

        const float4 U   = mu[s];           // wave-uniform broadcast loads
        const float base = mb[s];
        const int   aj   = maj[s];
        const int   ai   = mai[s];
        const int   sIdx = slotOf[ai] - 1;  // zero-based protocol
        if ((unsigned)sIdx >= ACAP) continue;

        float rbf[KRBF];
#pragma unroll
        for (int kk = 0; kk < KRBF; kk++)
            rbf[kk] = U.w * __sinf((float)(kk + 1) * base);

        float fn[11];
#pragma unroll 1
        for (int k = 0; k < 11; k++) {      // unroll 1: cap VGPR pressure
            float acc = 0.0f;
#pragma unroll
            for (int kk = 0; kk < KRBF; kk++)
                acc += rbf[kk] * rbf_w[k * (KRBF * CCH) + kk * CCH + c];
            fn[k] = acc;
        }

        const int cj = aj * CCH + c;
        const float s0 = t0[cj];
        float v[3];
#pragma unroll
        for (int a = 0; a < 3; a++) v[a] = t1[cj * 3 + a];
        float M[9];
#pragma unroll
        for (int e = 0; e < 9; e++) M[e] = t2[cj * 9 + e];

        const float u[3] = { U.x, U.y, U.z };
        const float dvu = v[0] * u[0] + v[1] * u[1] + v[2] * u[2];
        float Mu[3];
#pragma unroll
        for (int a = 0; a < 3; a++)
            Mu[a] = M[a * 3] * u[0] + M[a * 3 + 1] * u[1] + M[a * 3 + 2] * u[2];
        const float uMu = u[0] * Mu[0] + u[1] * Mu[1] + u[2] * Mu[2];

        float* dst = agg + ((size_t)sIdx * 13) * CCH + c;
        atomicAdd(&dst[0], fn[0] * s0 + fn[4] * dvu + fn[9] * uMu);
#pragma unroll
        for (int a = 0; a < 3; a++)
            atomicAdd(&dst[(1 + a) * CCH],
                      fn[1] * s0 * u[a] + fn[3] * v[a] + fn[6] * dvu * u[a] + fn[8] * Mu[a]);
#pragma unroll
        for (int a = 0; a < 3; a++) {
            const float ta = fn[2] * s0 * u[a] + fn[5] * v[a] + fn[10] * Mu[a];
#pragma unroll
            for (int b = 0; b < 3; b++)
                atomicAdd(&dst[(4 + a * 3 + b) * CCH], ta * u[b] + fn[7] * M[a * 3 + b]);
        }
    }
}

// ---------------------------------------------------------------------------
// Phase C: MFMA self-interaction (R3-proven structure, unchanged):
//   staging/store: `#pragma unroll 1` + depth-1 cur/nxt pipeline (2 loads in
//   flight at 8 payload regs -- the 13x full prefetch spilled at every cap).
//   PST=72 plane stride (conflicts 4.04M -> 2.28M).
// ---------------------------------------------------------------------------
__device__ __forceinline__ const float* stage_src(
    const float* __restrict__ t0, const float* __restrict__ t1,
    const float* __restrict__ t2, int n0, int f4, int& atom, int& f)
{
    atom = f4 / 208;                 // 208 float4 per atom
    f = (f4 - atom * 208) * 4;       // element offset in [0,832)
    const int n = n0 + atom;
    if (f < 64)  return t0 + (size_t)n * 64 + f;
    if (f < 256) return t1 + (size_t)n * 192 + (f - 64);
    return t2 + (size_t)n * 576 + (f - 256);
}

__global__ __launch_bounds__(256, 4) void si_mfma_kernel(
    const float* __restrict__ t0,
    const float* __restrict__ t1,
    const float* __restrict__ t2,
    const int*   __restrict__ slotOf,
    const float* __restrict__ agg,          // [ACAP * 13 * 64], plane-major
    const short* __restrict__ wfpre,        // [4][3][2][64][8] bf16
    const float* __restrict__ b0,
    const float* __restrict__ actw,
    float* __restrict__ out0,
    float* __restrict__ out1,
    float* __restrict__ out2)
{
    __shared__ __align__(16) short Xl[16 * XSTRIDE];   // 29,952 B
    const int tid  = threadIdx.x;
    const int lane = tid & 63;
    const int wid  = tid >> 6;
    const int n0   = blockIdx.x * 16;

    // --- staging: depth-1 pipelined loop (2 loads in flight, 8 payload regs) ---
    {
        int atomc, fc;
        const float* p0 = stage_src(t0, t1, t2, n0, tid, atomc, fc);
        float4 cur = *(const float4*)p0;
#pragma unroll 1
        for (int i = 0; i < 13; i++) {
            float4 nxt = make_float4(0.f, 0.f, 0.f, 0.f);
            int atomn = 0, fnx = 0;
            if (i < 12) {
                const float* pn = stage_src(t0, t1, t2, n0, tid + (i + 1) * 256, atomn, fnx);
                nxt = *(const float4*)pn;    // issued before cur is consumed
            }
            short* xr = &Xl[atomc * XSTRIDE];
            if (fc < 64) {
                v4s p; p[0] = f2bf(cur.x); p[1] = f2bf(cur.y);
                p[2] = f2bf(cur.z); p[3] = f2bf(cur.w);
                *(v4s*)&xr[fc] = p;              // plane 0 contiguous
            } else if (fc < 256) {
                const int r0 = fc - 64;
                const float vv[4] = { cur.x, cur.y, cur.z, cur.w };
#pragma unroll
                for (int j = 0; j < 4; j++) {
                    const int rem = r0 + j;
                    xr[(1 + rem % 3) * PST + rem / 3] = f2bf(vv[j]);
                }
            } else {
                const int r0 = fc - 256;
                const float vv[4] = { cur.x, cur.y, cur.z, cur.w };
#pragma unroll
                for (int j = 0; j < 4; j++) {
                    const int rem = r0 + j;
                    xr[(4 + rem % 9) * PST + rem / 9] = f2bf(vv[j]);
                }
            }
            cur = nxt; atomc = atomn; fc = fnx;
        }
    }
    __syncthreads();

    // --- agg add: slotOf as 4x int4, atom loop fully unrolled (static idx) ---
    {
        const int c = lane;
        int slots[16];
#pragma unroll
        for (int q = 0; q < 4; q++) {
            const int4 s4 = *(const int4*)&slotOf[n0 + q * 4];
            slots[q * 4 + 0] = s4.x; slots[q * 4 + 1] = s4.y;
            slots[q * 4 + 2] = s4.z; slots[q * 4 + 3] = s4.w;
        }
#pragma unroll
        for (int atom = 0; atom < 16; atom++) {
            const int slot = slots[atom] - 1;        // zero-based protocol
            if ((unsigned)slot >= ACAP) continue;    // block-uniform skip (~85%)
            short* xr = &Xl[atom * XSTRIDE];
            const float* ap = agg + ((size_t)slot * 13) * CCH + c;
            // wave wid owns planes wid, wid+4, wid+8 (+12 for wid==0):
            // issue the global loads first, then the LDS RMWs.
            const float g0 = ap[wid * CCH];
            const float g1 = ap[(wid + 4) * CCH];
            const float g2 = ap[(wid + 8) * CCH];
            const int o0 = wid * PST + c;
            const int o1 = (wid + 4) * PST + c;
            const int o2 = (wid + 8) * PST + c;
            if (wid == 0) {                           // wave-uniform branch
                const float g3 = ap[12 * CCH];
                const int o3 = 12 * PST + c;
                xr[o3] = f2bf(bf2f(xr[o3]) + g3);
            }
            xr[o0] = f2bf(bf2f(xr[o0]) + g0);
            xr[o1] = f2bf(bf2f(xr[o1]) + g1);
            xr[o2] = f2bf(bf2f(xr[o2]) + g2);
        }
    }
    __syncthreads();

    const int ocol = wid * 16 + (lane & 15);
    // --- W fragments: 6 coalesced b128 loads (loaded late: VGPR peak ctrl) ---
    v8s wf[3][2];
#pragma unroll
    for (int w = 0; w < 3; w++)
#pragma unroll
        for (int h = 0; h < 2; h++)
            wf[w][h] = *(const v8s*)&wfpre[(((wid * 3 + w) * 2 + h) * 64 + lane) * 8];

    // --- 26 MFMAs: 13 planes x 2 k-halves ---
    v4f acc[13] = {};
    const int abase = (lane & 15) * XSTRIDE + (lane >> 4) * 8;
#pragma unroll
    for (int p = 0; p < 13; p++) {
        const int w = (p == 0) ? 0 : (p < 4 ? 1 : 2);
#pragma unroll
        for (int h = 0; h < 2; h++) {
            const v8s a = *(const v8s*)&Xl[abase + p * PST + h * 32];
            acc[p] = __builtin_amdgcn_mfma_f32_16x16x32_bf16(a, wf[w][h], acc[p], 0, 0, 0);
        }
    }
    __syncthreads();   // all MFMA A-reads done before in-place overwrite

    // --- epilogue: gates + residual, RMW in-place (lane-owned positions) ---
    const float aw0  = actw[ocol];
    const float aw1  = actw[CCH + ocol];
    const float aw2  = actw[2 * CCH + ocol];
    const float bias = b0[ocol];
#pragma unroll
    for (int r = 0; r < 4; r++) {
        const int al = (lane >> 4) * 4 + r;      // atom-in-block (C/D row)
        short* xr = &Xl[al * XSTRIDE];

        const float y0 = acc[0][r] + bias;
        const float z0 = y0 * sigm(aw0 * y0);
        xr[ocol] = f2bf(z0 + bf2f(xr[ocol]));

        float nn = 1e-12f;
#pragma unroll
        for (int a = 0; a < 3; a++) nn += acc[1 + a][r] * acc[1 + a][r];
        const float g1 = sigm(aw1 * sqrtf(nn));
#pragma unroll
        for (int a = 0; a < 3; a++) {
            const int off = (1 + a) * PST + ocol;
            xr[off] = f2bf(acc[1 + a][r] * g1 + bf2f(xr[off]));
        }

        float s2 = 1e-12f;
#pragma unroll
        for (int e = 0; e < 9; e++) s2 += acc[4 + e][r] * acc[4 + e][r];
        const float g2 = sigm(aw2 * sqrtf(s2));
#pragma unroll
        for (int e = 0; e < 9; e++) {
            const int off = (4 + e) * PST + ocol;
            xr[off] = f2bf(acc[4 + e][r] * g2 + bf2f(xr[off]));
        }
    }
    __syncthreads();

    // --- store: unroll-1 loop mirroring staging mapping (no bulk hoisting) ---
#pragma unroll 1
    for (int i = 0; i < 13; i++) {
        const int f4   = tid + i * 256;
        const int atom = f4 / 208;
        const int f    = (f4 - atom * 208) * 4;
        const int n    = n0 + atom;
        const short* xr = &Xl[atom * XSTRIDE];
        float4 v;
        float* dst;
        if (f < 64) {
            const v4s p = *(const v4s*)&xr[f];
            v.x = bf2f(p[0]); v.y = bf2f(p[1]); v.z = bf2f(p[2]); v.w = bf2f(p[3]);
            dst = out0 + (size_t)n * 64 + f;
        } else if (f < 256) {
            const int r0 = f - 64;
            float vv[4];
#pragma unroll
            for (int j = 0; j < 4; j++) {
                const int rem = r0 + j;
                vv[j] = bf2f(xr[(1 + rem % 3) * PST + rem / 3]);
            }
            v.x = vv[0]; v.y = vv[1]; v.z = vv[2]; v.w = vv[3];
            dst = out1 + (size_t)n * 192 + r0;
        } else {
            const int r0 = f - 256;
            float vv[4];
#pragma unroll
            for (int j = 0; j < 4; j++) {
                const int rem = r0 + j;
                vv[j] = bf2f(xr[(4 + rem % 9) * PST + rem / 9]);
            }
            v.x = vv[0]; v.y = vv[1]; v.z = vv[2]; v.w = vv[3];
            dst = out2 + (size_t)n * 576 + r0;
        }
        *(float4*)dst = v;
    }
}

extern "C" void kernel_launch(void* const* d_in, const int* in_sizes, int n_in,
                              void* d_out, int out_size, void* d_ws, size_t ws_size,
                              hipStream_t stream) {
    const float* t0     = (const float*)d_in[0];
    const float* t1     = (const float*)d_in[1];
    const float* t2     = (const float*)d_in[2];
    const float* coords = (const float*)d_in[3];
    const int*   eidx   = (const int*)d_in[4];
    const float* rbfw   = (const float*)d_in[5];
    const float* w0     = (const float*)d_in[6];
    const float* b0     = (const float*)d_in[7];
    const float* w1     = (const float*)d_in[8];
    const float* w2     = (const float*)d_in[9];
    const float* actw   = (const float*)d_in[10];

    // Workspace: agg | mu | mb | maj | mai | wfpre | slotOf | cnts(1024 ints)
    float*  agg    = (float*)d_ws;                       // ACAP*832 floats (20 MB)
    float4* mu     = (float4*)(agg + (size_t)ACAP * FLAT);
    float*  mb     = (float*)(mu + MCAP);
    int*    maj    = (int*)(mb + MCAP);
    int*    mai    = maj + MCAP;
    short*  wfpre  = (short*)(mai + MCAP);               // 12288 bf16 (24.6 KB)
    int*    slotOf = (int*)(wfpre + 12288);
    int*    cnts   = slotOf + N_ATOMS;
    const size_t wsNeed = (size_t)ACAP * FLAT * 4 + (size_t)MCAP * 28
                        + 12288 * 2 + (size_t)N_ATOMS * 4 + 4096;
    if (ws_size < wsNeed) return;

    // Zero slotOf + sharded counters (84 KB): agg slots are cooperatively
    // zeroed by the winner's wave in edge_wfrag; mu/mb/maj/mai/wfpre are
    // write-before-read.
    hipMemsetAsync(slotOf, 0, (size_t)N_ATOMS * sizeof(int) + 4096, stream);

    float* o0 = (float*)d_out;
    float* o1 = o0 + (size_t)N_ATOMS * CCH;
    float* o2 = o1 + (size_t)N_ATOMS * CCH * 3;

    edge_wfrag_kernel<<<EF_BLOCKS + 48, 256, 0, stream>>>(
        coords, eidx, w0, w1, w2, mu, mb, maj, mai, slotOf, cnts, wfpre, agg);

    msg_scan_kernel<<<832, 256, 0, stream>>>(
        t0, t1, t2, rbfw, mu, mb, maj, mai, slotOf, cnts, agg);

    si_mfma_kernel<<<N_ATOMS / 16, 256, 0, stream>>>(
        t0, t1, t2, slotOf, agg, wfpre, b0, actw, o0, o1, o2);
}

// Round 5
// 167.513 us; speedup vs baseline: 1.6289x; 1.0373x over previous
//
#include <hip/hip_runtime.h>
#include <hip/hip_bf16.h>

// Problem constants (SOnEquivalentLayer)
#define N_ATOMS 20000
#define N_EDGES 200000
#define CCH     64      // channels
#define KRBF    20      // radial features
#define RCUT    5.0f
#define INV_NORM 0.1f   // 1/norm_factor
#define PI_F    3.14159265358979323846f
#define MCAP    20000   // message pool capacity (~6x expected ~3.3k active edges)
#define ACAP    6000    // active-atom capacity (~2x expected ~3.0k)
#define NSHARD  16      // counter shards (separate cache lines)
#define SEGM    (MCAP / NSHARD)   // 1250 msgs per shard (~206 expected)
#define ASEG    (ACAP / NSHARD)   // 375 atom slots per shard (~190 expected)
// LDS geometry: plane stride 72 shorts (144B) keeps 16B alignment for the
// b128 MFMA A-reads AND staggers plane p's base to bank 4p (bank conflicts
// 4.04M -> 2.28M cycles measured R0->R1).
#define PST     72
#define XSTRIDE (13 * PST)   // 936 shorts per atom row; 936*2*16 = 29,952 B LDS
#define FLAT    832          // 13*64 values per atom
#define EF_BLOCKS 782        // ceil(N_EDGES/256)

// counters region: 1024 ints (4 KB). cnt0[i] at [i*32], cnt1[i] at [512+i*32]
#define CNT0(c, i) (c)[(i) * 32]
#define CNT1(c, i) (c)[512 + (i) * 32]

typedef short v8s __attribute__((ext_vector_type(8)));   // 8 bf16 MFMA A/B frag
typedef short v4s __attribute__((ext_vector_type(4)));   // 4 bf16
typedef float v4f __attribute__((ext_vector_type(4)));   // 4 fp32 MFMA C/D frag

__device__ __forceinline__ float sigm(float x) { return 1.0f / (1.0f + __expf(-x)); }

// Native cast -> compiler emits v_cvt_pk_bf16_f32 (RNE), ~1 op / 2 elems.
// (R4 post-mortem: manual bit-twiddle RNE was ~4 VALU ops/elem and defeated
// the hw path; 52 conversions/thread in stage+store made VALUBusy 50%.)
__device__ __forceinline__ short f2bf(float x) {
    __bf16 b = (__bf16)x;
    short s;
    __builtin_memcpy(&s, &b, sizeof(s));
    return s;
}
__device__ __forceinline__ float bf2f(short b) {
    union { unsigned u; float f; } v; v.u = ((unsigned)(unsigned short)b) << 16;
    return v.f;
}

// ---------------------------------------------------------------------------
// Phase A (fused): edge cutoff filter + one-time W-fragment precompute.
// 16-way sharded counters + wave-aggregated allocation + cooperative zeroing
// (R4: 68us serialization chain -> below top-5).
// slotOf protocol: 0 = unassigned, stored = slot+1, ACAP+1 = overflow/invalid.
// ---------------------------------------------------------------------------
__global__ __launch_bounds__(256) void edge_wfrag_kernel(
    const float* __restrict__ coords,
    const int*   __restrict__ edge_index,
    const float* __restrict__ w0,
    const float* __restrict__ w1,
    const float* __restrict__ w2,
    float4*      __restrict__ mu,
    float*       __restrict__ mb,
    int*         __restrict__ maj,
    int*         __restrict__ mai,
    int*         __restrict__ slotOf,
    int*         __restrict__ cnts,
    short*       __restrict__ wfpre,
    float*       __restrict__ agg)
{
    if (blockIdx.x >= EF_BLOCKS) {
        // --- wfrag part: layout [wid][way][half][lane][8] bf16 ---
        const int id   = (blockIdx.x - EF_BLOCKS) * 256 + threadIdx.x; // 48*256
        const int j    = id & 7;
        const int lane = (id >> 3) & 63;
        const int h    = (id >> 9) & 1;
        const int rest = id >> 10;               // wid*3 + w, in [0,12)
        const int w    = rest % 3;
        const int wid  = rest / 3;
        const float* Ws = (w == 0) ? w0 : (w == 1) ? w1 : w2;
        const int k = h * 32 + (lane >> 4) * 8 + j;      // input channel
        const int o = wid * 16 + (lane & 15);            // output channel
        wfpre[id] = f2bf(Ws[k * CCH + o]);
        return;
    }

    const int e     = blockIdx.x * 256 + threadIdx.x;
    const int lane  = threadIdx.x & 63;
    const int shard = blockIdx.x & (NSHARD - 1);

    bool alive = (e < N_EDGES);
    int ai = 0, aj = 0;
    float rx = 0.f, ry = 0.f, rz = 0.f, d = 1.0f;
    if (alive) {
        ai = edge_index[e];
        aj = edge_index[N_EDGES + e];
        rx = coords[aj * 3 + 0] - coords[ai * 3 + 0];
        ry = coords[aj * 3 + 1] - coords[ai * 3 + 1];
        rz = coords[aj * 3 + 2] - coords[ai * 3 + 2];
        d  = sqrtf(rx * rx + ry * ry + rz * rz + 1e-12f);
        if (d >= RCUT) alive = false;   // fc == 0 exactly -> zero contribution
    }

    int myZeroSlot = -1;
    if (alive) {                        // exec == surviving lanes
        const float inv_d = 1.0f / d;
        const float base  = PI_F * (d * (1.0f / RCUT));
        const float fcv   = 0.5f * (cosf(base) + 1.0f);
        const float coef  = 0.632455532033676f * fcv * inv_d * INV_NORM;

        // wave-aggregated message-slot allocation (1 atomic per wave)
        const unsigned long long m = __ballot(1);
        const int pfx = __popcll(m & ((1ull << lane) - 1ull));
        int wbase = 0;
        if (pfx == 0) wbase = atomicAdd(&CNT0(cnts, shard), __popcll(m));
        wbase = __builtin_amdgcn_readfirstlane(wbase);
        const int loc = wbase + pfx;
        if (loc < SEGM) {
            const int slot = shard * SEGM + loc;
            mu[slot]  = make_float4(rx * inv_d, ry * inv_d, rz * inv_d, coef);
            mb[slot]  = base;
            maj[slot] = aj;
            mai[slot] = ai;
        }

        if (atomicCAS(&slotOf[ai], 0, -2) == 0) {   // exec == winner lanes
            const unsigned long long wm = __ballot(1);
            const int wpfx = __popcll(wm & ((1ull << lane) - 1ull));
            int wb = 0;
            if (wpfx == 0) wb = atomicAdd(&CNT1(cnts, shard), __popcll(wm));
            wb = __builtin_amdgcn_readfirstlane(wb);
            const int sl = wb + wpfx;
            if (sl < ASEG) {
                const int g = shard * ASEG + sl;
                slotOf[ai] = g + 1;                  // stored value = slot+1
                myZeroSlot = g;
            } else {
                slotOf[ai] = ACAP + 1;               // overflow -> invalid
            }
        }
    }

    // full exec: cooperative zero of each winner's agg slot (coalesced)
    unsigned long long zm = __ballot(myZeroSlot >= 0);
    while (zm) {
        const int src = (int)__builtin_ctzll(zm);
        zm &= zm - 1;
        const int g = __shfl(myZeroSlot, src);
        float4* az = (float4*)(agg + (size_t)g * FLAT);
#pragma unroll
        for (int q = 0; q < 4; q++) {
            const int idx = lane + q * 64;
            if (idx < FLAT / 4) az[idx] = make_float4(0.f, 0.f, 0.f, 0.f);
        }
    }
}

// ---------------------------------------------------------------------------
// Phase B: wave-per-message scan over 16 message segments. PLANE-MAJOR agg
// (agg[(slot*13+p)*64+c]): every wave-atomic hits 64 contiguous floats.
// Segment lookup per message is an unrolled constant-indexed select chain
// (registers only -- runtime-indexed local arrays go to scratch, rule #20).
// ---------------------------------------------------------------------------
__global__ __launch_bounds__(256, 4) void msg_scan_kernel(
    const float* __restrict__ t0,
    const float* __restrict__ t1,
    const float* __restrict__ t2,
    const float* __restrict__ rbf_w,
    const float4* __restrict__ mu,
    const float* __restrict__ mb,
    const int*   __restrict__ maj,
    const int*   __restrict__ mai,
    const int*   __restrict__ slotOf,
    const int*   __restrict__ cnts,
    float*       __restrict__ agg)          // [ACAP * 13 * 64], slot-zeroed
{
    const int w    = (int)((blockIdx.x * 256 + threadIdx.x) >> 6);
    const int c    = threadIdx.x & 63;
    const int nw   = gridDim.x * 4;

    int pr[NSHARD];      // prefix before shard i (const-indexed in unrolls)
    int run = 0;
#pragma unroll
    for (int i = 0; i < NSHARD; i++) {
        pr[i] = run;
        run += min(CNT0(cnts, i), SEGM);
    }
    const int T = run;

    for (int mg = w; mg < T; mg += nw) {
        int s = mg;                          // pooled slot for segment 0
#pragma unroll
        for (int i = 1; i < NSHARD; i++)
            if (mg >= pr[i]) s = i * SEGM + (mg - pr[i]);

        const float4 U   = mu[s];           // wave-uniform broadcast loads
        const float base = mb[s];
        const int   aj   = maj[s];
        const int   ai   = mai[s];
        const int   sIdx = slotOf[ai] - 1;  // zero-based protocol
        if ((unsigned)sIdx >= ACAP) continue;

        float rbf[KRBF];
#pragma unroll
        for (int kk = 0; kk < KRBF; kk++)
            rbf[kk] = U.w * __sinf((float)(kk + 1) * base);

        float fn[11];
#pragma unroll 1
        for (int k = 0; k < 11; k++) {      // unroll 1: cap VGPR pressure
            float acc = 0.0f;
#pragma unroll
            for (int kk = 0; kk < KRBF; kk++)
                acc += rbf[kk] * rbf_w[k * (KRBF * CCH) + kk * CCH + c];
            fn[k] = acc;
        }

        const int cj = aj * CCH + c;
        const float s0 = t0[cj];
        float v[3];
#pragma unroll
        for (int a = 0; a < 3; a++) v[a] = t1[cj * 3 + a];
        float M[9];
#pragma unroll
        for (int e = 0; e < 9; e++) M[e] = t2[cj * 9 + e];

        const float u[3] = { U.x, U.y, U.z };
        const float dvu = v[0] * u[0] + v[1] * u[1] + v[2] * u[2];
        float Mu[3];
#pragma unroll
        for (int a = 0; a < 3; a++)
            Mu[a] = M[a * 3] * u[0] + M[a * 3 + 1] * u[1] + M[a * 3 + 2] * u[2];
        const float uMu = u[0] * Mu[0] + u[1] * Mu[1] + u[2] * Mu[2];

        float* dst = agg + ((size_t)sIdx * 13) * CCH + c;
        atomicAdd(&dst[0], fn[0] * s0 + fn[4] * dvu + fn[9] * uMu);
#pragma unroll
        for (int a = 0; a < 3; a++)
            atomicAdd(&dst[(1 + a) * CCH],
                      fn[1] * s0 * u[a] + fn[3] * v[a] + fn[6] * dvu * u[a] + fn[8] * Mu[a]);
#pragma unroll
        for (int a = 0; a < 3; a++) {
            const float ta = fn[2] * s0 * u[a] + fn[5] * v[a] + fn[10] * Mu[a];
#pragma unroll
            for (int b = 0; b < 3; b++)
                atomicAdd(&dst[(4 + a * 3 + b) * CCH], ta * u[b] + fn[7] * M[a * 3 + b]);
        }
    }
}

// ---------------------------------------------------------------------------
// Phase C: MFMA self-interaction. v6 (VALU diet):
//   NEW thread->element mapping: atom = tid>>4 (free), tf = (tid&15)*4,
//   f = tf + i*64. Kills the /208 %208 magic-division per iteration and makes
//   the t0/t1/t2 region branches wave-uniform scalar branches. Coalescing
//   preserved: i=0 is one contiguous 1KB wave read; t1/t2 are 256B segments
//   per atom group.
//   f2bf now a native __bf16 cast -> v_cvt_pk_bf16_f32 (was 4 ops/elem).
//   Structure unchanged (R3/R4-proven): unroll-1 + depth-1 cur/nxt pipeline
//   (full 13x prefetch spilled at every cap), PST=72, launch_bounds(256,4).
// ---------------------------------------------------------------------------
__device__ __forceinline__ const float* stage_src(
    const float* __restrict__ t0, const float* __restrict__ t1,
    const float* __restrict__ t2, int n, int tf, int i)
{
    const int f = tf + i * 64;
    if (i == 0) return t0 + (size_t)n * 64 + f;          // wave-uniform branch
    if (i < 4)  return t1 + (size_t)n * 192 + (f - 64);
    return t2 + (size_t)n * 576 + (f - 256);
}

__global__ __launch_bounds__(256, 4) void si_mfma_kernel(
    const float* __restrict__ t0,
    const float* __restrict__ t1,
    const float* __restrict__ t2,
    const int*   __restrict__ slotOf,
    const float* __restrict__ agg,          // [ACAP * 13 * 64], plane-major
    const short* __restrict__ wfpre,        // [4][3][2][64][8] bf16
    const float* __restrict__ b0,
    const float* __restrict__ actw,
    float* __restrict__ out0,
    float* __restrict__ out1,
    float* __restrict__ out2)
{
    __shared__ __align__(16) short Xl[16 * XSTRIDE];   // 29,952 B
    const int tid  = threadIdx.x;
    const int lane = tid & 63;
    const int wid  = tid >> 6;
    const int n0   = blockIdx.x * 16;
    const int atom = tid >> 4;               // 16 threads per atom
    const int tf   = (tid & 15) * 4;         // float4 offset within 64-chunk
    const int n    = n0 + atom;

    // --- staging: depth-1 pipelined loop (2 loads in flight, 8 payload regs) ---
    {
        short* xr = &Xl[atom * XSTRIDE];
        float4 cur = *(const float4*)stage_src(t0, t1, t2, n, tf, 0);
#pragma unroll 1
        for (int i = 0; i < 13; i++) {
            float4 nxt = make_float4(0.f, 0.f, 0.f, 0.f);
            if (i < 12)
                nxt = *(const float4*)stage_src(t0, t1, t2, n, tf, i + 1);
            if (i == 0) {
                v4s p; p[0] = f2bf(cur.x); p[1] = f2bf(cur.y);
                p[2] = f2bf(cur.z); p[3] = f2bf(cur.w);
                *(v4s*)&xr[tf] = p;              // plane 0 contiguous
            } else if (i < 4) {
                const int r0 = tf + (i - 1) * 64;    // t1 element index
                const float vv[4] = { cur.x, cur.y, cur.z, cur.w };
#pragma unroll
                for (int j = 0; j < 4; j++) {
                    const int rem = r0 + j;
                    xr[(1 + rem % 3) * PST + rem / 3] = f2bf(vv[j]);
                }
            } else {
                const int r0 = tf + (i - 4) * 64;    // t2 element index
                const float vv[4] = { cur.x, cur.y, cur.z, cur.w };
#pragma unroll
                for (int j = 0; j < 4; j++) {
                    const int rem = r0 + j;
                    xr[(4 + rem % 9) * PST + rem / 9] = f2bf(vv[j]);
                }
            }
            cur = nxt;
        }
    }
    __syncthreads();

    // --- agg add: slotOf as 4x int4, atom loop fully unrolled (static idx) ---
    {
        const int c = lane;
        int slots[16];
#pragma unroll
        for (int q = 0; q < 4; q++) {
            const int4 s4 = *(const int4*)&slotOf[n0 + q * 4];
            slots[q * 4 + 0] = s4.x; slots[q * 4 + 1] = s4.y;
            slots[q * 4 + 2] = s4.z; slots[q * 4 + 3] = s4.w;
        }
#pragma unroll
        for (int at = 0; at < 16; at++) {
            const int slot = slots[at] - 1;          // zero-based protocol
            if ((unsigned)slot >= ACAP) continue;    // block-uniform skip (~85%)
            short* xr = &Xl[at * XSTRIDE];
            const float* ap = agg + ((size_t)slot * 13) * CCH + c;
            // wave wid owns planes wid, wid+4, wid+8 (+12 for wid==0):
            // issue the global loads first, then the LDS RMWs.
            const float g0 = ap[wid * CCH];
            const float g1 = ap[(wid + 4) * CCH];
            const float g2 = ap[(wid + 8) * CCH];
            const int o0 = wid * PST + c;
            const int o1 = (wid + 4) * PST + c;
            const int o2 = (wid + 8) * PST + c;
            if (wid == 0) {                           // wave-uniform branch
                const float g3 = ap[12 * CCH];
                const int o3 = 12 * PST + c;
                xr[o3] = f2bf(bf2f(xr[o3]) + g3);
            }
            xr[o0] = f2bf(bf2f(xr[o0]) + g0);
            xr[o1] = f2bf(bf2f(xr[o1]) + g1);
            xr[o2] = f2bf(bf2f(xr[o2]) + g2);
        }
    }
    __syncthreads();

    const int ocol = wid * 16 + (lane & 15);
    // --- W fragments: 6 coalesced b128 loads (loaded late: VGPR peak ctrl) ---
    v8s wf[3][2];
#pragma unroll
    for (int w = 0; w < 3; w++)
#pragma unroll
        for (int h = 0; h < 2; h++)
            wf[w][h] = *(const v8s*)&wfpre[(((wid * 3 + w) * 2 + h) * 64 + lane) * 8];

    // --- 26 MFMAs: 13 planes x 2 k-halves ---
    v4f acc[13] = {};
    const int abase = (lane & 15) * XSTRIDE + (lane >> 4) * 8;
#pragma unroll
    for (int p = 0; p < 13; p++) {
        const int w = (p == 0) ? 0 : (p < 4 ? 1 : 2);
#pragma unroll
        for (int h = 0; h < 2; h++) {
            const v8s a = *(const v8s*)&Xl[abase + p * PST + h * 32];
            acc[p] = __builtin_amdgcn_mfma_f32_16x16x32_bf16(a, wf[w][h], acc[p], 0, 0, 0);
        }
    }
    __syncthreads();   // all MFMA A-reads done before in-place overwrite

    // --- epilogue: gates + residual, RMW in-place (lane-owned positions) ---
    const float aw0  = actw[ocol];
    const float aw1  = actw[CCH + ocol];
    const float aw2  = actw[2 * CCH + ocol];
    const float bias = b0[ocol];
#pragma unroll
    for (int r = 0; r < 4; r++) {
        const int al = (lane >> 4) * 4 + r;      // atom-in-block (C/D row)
        short* xr = &Xl[al * XSTRIDE];

        const float y0 = acc[0][r] + bias;
        const float z0 = y0 * sigm(aw0 * y0);
        xr[ocol] = f2bf(z0 + bf2f(xr[ocol]));

        float nn = 1e-12f;
#pragma unroll
        for (int a = 0; a < 3; a++) nn += acc[1 + a][r] * acc[1 + a][r];
        const float g1 = sigm(aw1 * sqrtf(nn));
#pragma unroll
        for (int a = 0; a < 3; a++) {
            const int off = (1 + a) * PST + ocol;
            xr[off] = f2bf(acc[1 + a][r] * g1 + bf2f(xr[off]));
        }

        float s2 = 1e-12f;
#pragma unroll
        for (int e = 0; e < 9; e++) s2 += acc[4 + e][r] * acc[4 + e][r];
        const float g2 = sigm(aw2 * sqrtf(s2));
#pragma unroll
        for (int e = 0; e < 9; e++) {
            const int off = (4 + e) * PST + ocol;
            xr[off] = f2bf(acc[4 + e][r] * g2 + bf2f(xr[off]));
        }
    }
    __syncthreads();

    // --- store: unroll-1 loop mirroring the new staging mapping ---
#pragma unroll 1
    for (int i = 0; i < 13; i++) {
        const short* xr = &Xl[atom * XSTRIDE];
        float4 v;
        float* dst;
        if (i == 0) {
            const v4s p = *(const v4s*)&xr[tf];
            v.x = bf2f(p[0]); v.y = bf2f(p[1]); v.z = bf2f(p[2]); v.w = bf2f(p[3]);
            dst = out0 + (size_t)n * 64 + tf;
        } else if (i < 4) {
            const int r0 = tf + (i - 1) * 64;
            float vv[4];
#pragma unroll
            for (int j = 0; j < 4; j++) {
                const int rem = r0 + j;
                vv[j] = bf2f(xr[(1 + rem % 3) * PST + rem / 3]);
            }
            v.x = vv[0]; v.y = vv[1]; v.z = vv[2]; v.w = vv[3];
            dst = out1 + (size_t)n * 192 + r0;
        } else {
            const int r0 = tf + (i - 4) * 64;
            float vv[4];
#pragma unroll
            for (int j = 0; j < 4; j++) {
                const int rem = r0 + j;
                vv[j] = bf2f(xr[(4 + rem % 9) * PST + rem / 9]);
            }
            v.x = vv[0]; v.y = vv[1]; v.z = vv[2]; v.w = vv[3];
            dst = out2 + (size_t)n * 576 + r0;
        }
        *(float4*)dst = v;
    }
}

extern "C" void kernel_launch(void* const* d_in, const int* in_sizes, int n_in,
                              void* d_out, int out_size, void* d_ws, size_t ws_size,
                              hipStream_t stream) {
    const float* t0     = (const float*)d_in[0];
    const float* t1     = (const float*)d_in[1];
    const float* t2     = (const float*)d_in[2];
    const float* coords = (const float*)d_in[3];
    const int*   eidx   = (const int*)d_in[4];
    const float* rbfw   = (const float*)d_in[5];
    const float* w0     = (const float*)d_in[6];
    const float* b0     = (const float*)d_in[7];
    const float* w1     = (const float*)d_in[8];
    const float* w2     = (const float*)d_in[9];
    const float* actw   = (const float*)d_in[10];

    // Workspace: agg | mu | mb | maj | mai | wfpre | slotOf | cnts(1024 ints)
    float*  agg    = (float*)d_ws;                       // ACAP*832 floats (20 MB)
    float4* mu     = (float4*)(agg + (size_t)ACAP * FLAT);
    float*  mb     = (float*)(mu + MCAP);
    int*    maj    = (int*)(mb + MCAP);
    int*    mai    = maj + MCAP;
    short*  wfpre  = (short*)(mai + MCAP);               // 12288 bf16 (24.6 KB)
    int*    slotOf = (int*)(wfpre + 12288);
    int*    cnts   = slotOf + N_ATOMS;
    const size_t wsNeed = (size_t)ACAP * FLAT * 4 + (size_t)MCAP * 28
                        + 12288 * 2 + (size_t)N_ATOMS * 4 + 4096;
    if (ws_size < wsNeed) return;

    // Zero slotOf + sharded counters (84 KB): agg slots are cooperatively
    // zeroed by the winner's wave in edge_wfrag; mu/mb/maj/mai/wfpre are
    // write-before-read.
    hipMemsetAsync(slotOf, 0, (size_t)N_ATOMS * sizeof(int) + 4096, stream);

    float* o0 = (float*)d_out;
    float* o1 = o0 + (size_t)N_ATOMS * CCH;
    float* o2 = o1 + (size_t)N_ATOMS * CCH * 3;

    edge_wfrag_kernel<<<EF_BLOCKS + 48, 256, 0, stream>>>(
        coords, eidx, w0, w1, w2, mu, mb, maj, mai, slotOf, cnts, wfpre, agg);

    msg_scan_kernel<<<832, 256, 0, stream>>>(
        t0, t1, t2, rbfw, mu, mb, maj, mai, slotOf, cnts, agg);

    si_mfma_kernel<<<N_ATOMS / 16, 256, 0, stream>>>(
        t0, t1, t2, slotOf, agg, wfpre, b0, actw, o0, o1, o2);
}